// Round 1
// baseline (1699.930 us; speedup 1.0000x reference)
//
#include <hip/hip_runtime.h>
#include <math.h>

#define BB   4
#define N1   8192
#define N2   2048
#define KNN  8
#define C1   256
#define C2   512
#define H0C  128
#define H2C  256
#define FIN  512
#define FOUT 256

// ---------------------------------------------------------------------------
// Kernel 1: KNN. One thread per query. pos2 staged in LDS. Top-8 kept in
// registers with static-index bubble insertion (no scratch). f64 distances so
// the ranking matches the (float64) numpy reference exactly.
// ---------------------------------------------------------------------------
__global__ __launch_bounds__(256) void knn_kernel(const float* __restrict__ pos1,
                                                  const float* __restrict__ pos2,
                                                  int* __restrict__ idx_out) {
    __shared__ float px[N2], py[N2], pz[N2];
    const int t = threadIdx.x;
    const int blocksPerB = N1 / 256;
    const int b = blockIdx.x / blocksPerB;
    const int n = (blockIdx.x % blocksPerB) * 256 + t;

    const float* p2b = pos2 + (size_t)b * 3 * N2;
    for (int i = t; i < N2; i += 256) px[i] = p2b[i];
    for (int i = t; i < N2; i += 256) py[i] = p2b[N2 + i];
    for (int i = t; i < N2; i += 256) pz[i] = p2b[2 * N2 + i];
    __syncthreads();

    const float* p1b = pos1 + (size_t)b * 3 * N1;
    const double qx = (double)p1b[n];
    const double qy = (double)p1b[N1 + n];
    const double qz = (double)p1b[2 * N1 + n];

    double bd[KNN];
    int    bi[KNN];
#pragma unroll
    for (int m = 0; m < KNN; ++m) { bd[m] = 1e300; bi[m] = 0; }

    for (int j = 0; j < N2; ++j) {
        double dx = (double)px[j] - qx;
        double dy = (double)py[j] - qy;
        double dz = (double)pz[j] - qz;
        double d2 = dx * dx + dy * dy + dz * dz;
        if (d2 < bd[KNN - 1]) {
            bd[KNN - 1] = d2; bi[KNN - 1] = j;
#pragma unroll
            for (int m = KNN - 1; m > 0; --m) {
                if (bd[m] < bd[m - 1]) {
                    double td = bd[m]; bd[m] = bd[m - 1]; bd[m - 1] = td;
                    int ti = bi[m]; bi[m] = bi[m - 1]; bi[m - 1] = ti;
                }
            }
        }
    }
    int* o = idx_out + ((size_t)b * N1 + n) * KNN;
#pragma unroll
    for (int m = 0; m < KNN; ++m) o[m] = bi[m];
}

// ---------------------------------------------------------------------------
// Kernel 2: G0t[b][j][c] = sum_{i<512} feature2[b][i][j] * w1_0[c][i]
// Stored point-major (j, c) so the main kernel's gather is coalesced.
// Tiled GEMM: 64 j x 128 c per block, K-chunks of 32.
// ---------------------------------------------------------------------------
__global__ __launch_bounds__(256) void g0_kernel(const float* __restrict__ f2,
                                                 const float* __restrict__ w10,
                                                 float* __restrict__ g0t) {
    __shared__ float At[32][68];    // [ii][jj]
    __shared__ float Wt[32][132];   // [ii][c]
    const int t  = threadIdx.x;
    const int b  = blockIdx.x >> 5;
    const int jt = (blockIdx.x & 31) * 64;
    const float* A = f2 + (size_t)b * C2 * N2;

    float acc[8][4];
#pragma unroll
    for (int r = 0; r < 8; ++r)
#pragma unroll
        for (int s = 0; s < 4; ++s) acc[r][s] = 0.f;

    const int jj  = t & 63, iw  = (t >> 6) * 8;   // A loads
    const int wc  = t >> 1, wih = (t & 1) * 16;   // W loads
    const int jg  = t & 7,  cg  = t >> 3;         // compute

    for (int i0 = 0; i0 < C2; i0 += 32) {
        __syncthreads();
#pragma unroll
        for (int u = 0; u < 8; ++u)
            At[iw + u][jj] = A[(size_t)(i0 + iw + u) * N2 + jt + jj];
#pragma unroll
        for (int u = 0; u < 16; ++u)
            Wt[wih + u][wc] = w10[(size_t)wc * 515 + i0 + wih + u];
        __syncthreads();
#pragma unroll
        for (int ii = 0; ii < 32; ++ii) {
            float a[8], w[4];
            *(float4*)&a[0] = *(const float4*)&At[ii][jg * 8];
            *(float4*)&a[4] = *(const float4*)&At[ii][jg * 8 + 4];
            *(float4*)&w[0] = *(const float4*)&Wt[ii][cg * 4];
#pragma unroll
            for (int r = 0; r < 8; ++r)
#pragma unroll
                for (int s = 0; s < 4; ++s) acc[r][s] += a[r] * w[s];
        }
    }
#pragma unroll
    for (int r = 0; r < 8; ++r) {
        int j = jt + jg * 8 + r;
        float4 v = make_float4(acc[r][0], acc[r][1], acc[r][2], acc[r][3]);
        *(float4*)&g0t[((size_t)b * N2 + j) * H0C + cg * 4] = v;
    }
}

// ---------------------------------------------------------------------------
// Kernel 3: fused main. 256 threads handle 8 queries (64 neighbor-points).
// Phase A: gather G0t + pos-diff correction -> h0 (relu)
// Phase B: layer1 128->128 (relu)           -> h1
// Phase C: layer2 128->256 (relu) + max over k -> s_x[:,0:256]
// Phase D: concat feature1, final 512->256 (relu) -> out
// ---------------------------------------------------------------------------
__global__ __launch_bounds__(256) void main_kernel(
    const int*   __restrict__ idxbuf,
    const float* __restrict__ g0t,
    const float* __restrict__ pos1,
    const float* __restrict__ pos2,
    const float* __restrict__ feature1,
    const float* __restrict__ w10, const float* __restrict__ s10, const float* __restrict__ b10,
    const float* __restrict__ w11, const float* __restrict__ s11, const float* __restrict__ b11,
    const float* __restrict__ w12, const float* __restrict__ s12, const float* __restrict__ b12,
    const float* __restrict__ w20, const float* __restrict__ s20, const float* __restrict__ b20,
    float* __restrict__ out) {

    __shared__ float s_h0[64][129];
    __shared__ float s_h1[64][129];
    __shared__ float s_w[32 * 260];
    __shared__ float s_x[8][516];
    __shared__ float s_sb[2][256];
    __shared__ float s_wp[3][128];
    __shared__ float s_pd[64][4];
    __shared__ int   s_idx[64];

    const int t  = threadIdx.x;
    const int b  = blockIdx.x >> 10;
    const int n0 = (blockIdx.x & 1023) << 3;

    // ---- setup ----
    if (t < 64)
        s_idx[t] = idxbuf[((size_t)b * N1 + n0 + (t >> 3)) * KNN + (t & 7)];
    if (t < 128) {
        s_wp[0][t] = w10[(size_t)t * 515 + 512];
        s_wp[1][t] = w10[(size_t)t * 515 + 513];
        s_wp[2][t] = w10[(size_t)t * 515 + 514];
        s_sb[0][t] = s10[t];
        s_sb[1][t] = b10[t];
    }
    __syncthreads();
    if (t < 64) {
        int j = s_idx[t];
        int n = n0 + (t >> 3);
        const float* p2b = pos2 + (size_t)b * 3 * N2;
        const float* p1b = pos1 + (size_t)b * 3 * N1;
        s_pd[t][0] = p2b[j]          - p1b[n];
        s_pd[t][1] = p2b[N2 + j]     - p1b[N1 + n];
        s_pd[t][2] = p2b[2 * N2 + j] - p1b[2 * N1 + n];
    }
    __syncthreads();

    // ---- Phase A: h0 ----
    {
        const int c = t & 127, ph = t >> 7;
        for (int pp = 0; pp < 64; pp += 2) {
            int p = pp + ph;
            int j = s_idx[p];
            float g = g0t[((size_t)b * N2 + j) * H0C + c];
            float v = g + s_wp[0][c] * s_pd[p][0]
                        + s_wp[1][c] * s_pd[p][1]
                        + s_wp[2][c] * s_pd[p][2];
            v = s_sb[0][c] * v + s_sb[1][c];
            s_h0[p][c] = v > 0.f ? v : 0.f;
        }
    }
    __syncthreads();
    if (t < 128) { s_sb[0][t] = s11[t]; s_sb[1][t] = b11[t]; }

    // ---- Phase B: layer1 128->128 ----
    {
        float acc[4][8];
#pragma unroll
        for (int r = 0; r < 4; ++r)
#pragma unroll
            for (int u = 0; u < 8; ++u) acc[r][u] = 0.f;
        const int pg = t >> 4, cg = t & 15;       // p0 = pg*4, c0 = cg*8
        const int lc = t >> 1, lih = (t & 1) * 16;
        for (int i0 = 0; i0 < 128; i0 += 32) {
            __syncthreads();
#pragma unroll
            for (int u4 = 0; u4 < 4; ++u4) {
                float4 v = *(const float4*)&w11[(size_t)lc * 128 + i0 + lih + u4 * 4];
                s_w[(lih + u4 * 4 + 0) * 132 + lc] = v.x;
                s_w[(lih + u4 * 4 + 1) * 132 + lc] = v.y;
                s_w[(lih + u4 * 4 + 2) * 132 + lc] = v.z;
                s_w[(lih + u4 * 4 + 3) * 132 + lc] = v.w;
            }
            __syncthreads();
#pragma unroll
            for (int ii = 0; ii < 32; ++ii) {
                float w[8];
                *(float4*)&w[0] = *(const float4*)&s_w[ii * 132 + cg * 8];
                *(float4*)&w[4] = *(const float4*)&s_w[ii * 132 + cg * 8 + 4];
#pragma unroll
                for (int r = 0; r < 4; ++r) {
                    float a = s_h0[pg * 4 + r][i0 + ii];
#pragma unroll
                    for (int u = 0; u < 8; ++u) acc[r][u] += a * w[u];
                }
            }
        }
        __syncthreads();
#pragma unroll
        for (int r = 0; r < 4; ++r)
#pragma unroll
            for (int u = 0; u < 8; ++u) {
                int c = cg * 8 + u;
                float v = s_sb[0][c] * acc[r][u] + s_sb[1][c];
                s_h1[pg * 4 + r][c] = v > 0.f ? v : 0.f;
            }
    }
    __syncthreads();
    { s_sb[0][t] = s12[t]; s_sb[1][t] = b12[t]; }   // 256 channels

    // ---- Phase C: layer2 128->256 + max over k ----
    {
        float acc[8][8];
#pragma unroll
        for (int k = 0; k < 8; ++k)
#pragma unroll
            for (int u = 0; u < 8; ++u) acc[k][u] = 0.f;
        const int q = t >> 5, cg = t & 31;        // c0 = cg*8
        for (int i0 = 0; i0 < 128; i0 += 32) {
            __syncthreads();
#pragma unroll
            for (int u4 = 0; u4 < 8; ++u4) {
                float4 v = *(const float4*)&w12[(size_t)t * 128 + i0 + u4 * 4];
                s_w[(u4 * 4 + 0) * 260 + t] = v.x;
                s_w[(u4 * 4 + 1) * 260 + t] = v.y;
                s_w[(u4 * 4 + 2) * 260 + t] = v.z;
                s_w[(u4 * 4 + 3) * 260 + t] = v.w;
            }
            __syncthreads();
#pragma unroll
            for (int ii = 0; ii < 32; ++ii) {
                float w[8];
                *(float4*)&w[0] = *(const float4*)&s_w[ii * 260 + cg * 8];
                *(float4*)&w[4] = *(const float4*)&s_w[ii * 260 + cg * 8 + 4];
#pragma unroll
                for (int k = 0; k < 8; ++k) {
                    float a = s_h1[q * 8 + k][i0 + ii];
#pragma unroll
                    for (int u = 0; u < 8; ++u) acc[k][u] += a * w[u];
                }
            }
        }
#pragma unroll
        for (int u = 0; u < 8; ++u) {
            int c = cg * 8 + u;
            float m = 0.f;
#pragma unroll
            for (int k = 0; k < 8; ++k) {
                float v = s_sb[0][c] * acc[k][u] + s_sb[1][c];
                v = v > 0.f ? v : 0.f;
                m = (k == 0) ? v : fmaxf(m, v);
            }
            s_x[q][c] = m;
        }
    }
    // feature1 columns into s_x[:, 256:512]
    {
        const float* f1b = feature1 + (size_t)b * C1 * N1 + n0;
#pragma unroll
        for (int q = 0; q < 8; ++q)
            s_x[q][256 + t] = f1b[(size_t)t * N1 + q];
    }
    __syncthreads();
    { s_sb[0][t] = s20[t]; s_sb[1][t] = b20[t]; }

    // ---- Phase D: final 512->256 ----
    {
        float acc[8];
#pragma unroll
        for (int u = 0; u < 8; ++u) acc[u] = 0.f;
        const int q = t >> 5, cg = t & 31;
        for (int i0 = 0; i0 < 512; i0 += 32) {
            __syncthreads();
#pragma unroll
            for (int u4 = 0; u4 < 8; ++u4) {
                float4 v = *(const float4*)&w20[(size_t)t * 512 + i0 + u4 * 4];
                s_w[(u4 * 4 + 0) * 260 + t] = v.x;
                s_w[(u4 * 4 + 1) * 260 + t] = v.y;
                s_w[(u4 * 4 + 2) * 260 + t] = v.z;
                s_w[(u4 * 4 + 3) * 260 + t] = v.w;
            }
            __syncthreads();
#pragma unroll
            for (int ii = 0; ii < 32; ++ii) {
                float w[8];
                *(float4*)&w[0] = *(const float4*)&s_w[ii * 260 + cg * 8];
                *(float4*)&w[4] = *(const float4*)&s_w[ii * 260 + cg * 8 + 4];
                float a = s_x[q][i0 + ii];
#pragma unroll
                for (int u = 0; u < 8; ++u) acc[u] += a * w[u];
            }
        }
        const int n = n0 + q;
#pragma unroll
        for (int u = 0; u < 8; ++u) {
            int c = cg * 8 + u;
            float v = s_sb[0][c] * acc[u] + s_sb[1][c];
            out[((size_t)b * FOUT + c) * N1 + n] = v > 0.f ? v : 0.f;
        }
    }
}

// ---------------------------------------------------------------------------
extern "C" void kernel_launch(void* const* d_in, const int* in_sizes, int n_in,
                              void* d_out, int out_size, void* d_ws, size_t ws_size,
                              hipStream_t stream) {
    (void)in_sizes; (void)n_in; (void)out_size; (void)ws_size;
    const float* pos1     = (const float*)d_in[0];
    const float* pos2     = (const float*)d_in[1];
    const float* feature1 = (const float*)d_in[2];
    const float* feature2 = (const float*)d_in[3];
    const float* w10 = (const float*)d_in[4];
    const float* s10 = (const float*)d_in[5];
    const float* b10 = (const float*)d_in[6];
    const float* w11 = (const float*)d_in[7];
    const float* s11 = (const float*)d_in[8];
    const float* b11 = (const float*)d_in[9];
    const float* w12 = (const float*)d_in[10];
    const float* s12 = (const float*)d_in[11];
    const float* b12 = (const float*)d_in[12];
    const float* w20 = (const float*)d_in[13];
    const float* s20 = (const float*)d_in[14];
    const float* b20 = (const float*)d_in[15];
    float* out = (float*)d_out;

    int*   idxbuf = (int*)d_ws;
    float* g0t    = (float*)((char*)d_ws + (size_t)BB * N1 * KNN * sizeof(int));

    knn_kernel<<<BB * (N1 / 256), 256, 0, stream>>>(pos1, pos2, idxbuf);
    g0_kernel<<<BB * (N2 / 64), 256, 0, stream>>>(feature2, w10, g0t);
    main_kernel<<<BB * (N1 / 8), 256, 0, stream>>>(
        idxbuf, g0t, pos1, pos2, feature1,
        w10, s10, b10, w11, s11, b11, w12, s12, b12, w20, s20, b20, out);
}

// Round 2
// 296.225 us; speedup vs baseline: 5.7387x; 5.7387x over previous
//
#include <hip/hip_runtime.h>

#define BB   4
#define N1   8192
#define N2   2048
#define KNN  8
#define C1   256
#define C2   512
#define NPART 4
#define CPART 512

typedef __attribute__((ext_vector_type(8))) short bf16x8;
typedef __attribute__((ext_vector_type(4))) float f32x4;

__device__ __forceinline__ unsigned short f2bf(float x) {
    union { float f; unsigned u; } v; v.f = x;
    return (unsigned short)((v.u + 0x7fffu + ((v.u >> 16) & 1u)) >> 16);
}

// ---------------------------------------------------------------------------
// KNN, 4-way candidate split: block = 256 queries x 512 candidates. f64
// distances (matches numpy f64 ref ranking; neighbor SET is all that matters
// since max-over-k is permutation invariant).
// ---------------------------------------------------------------------------
__global__ __launch_bounds__(256) void knn_part_kernel(const float* __restrict__ pos1,
                                                       const float* __restrict__ pos2,
                                                       double* __restrict__ dpart,
                                                       int* __restrict__ ipart) {
    __shared__ float px[CPART], py[CPART], pz[CPART];
    const int t = threadIdx.x;
    const int part = blockIdx.x & 3;
    const int tile = (blockIdx.x >> 2) & 31;
    const int b = blockIdx.x >> 7;
    const int n = tile * 256 + t;
    const int jbase = part * CPART;

    const float* p2b = pos2 + (size_t)b * 3 * N2 + jbase;
    for (int i = t; i < CPART; i += 256) {
        px[i] = p2b[i]; py[i] = p2b[N2 + i]; pz[i] = p2b[2 * N2 + i];
    }
    __syncthreads();

    const float* p1b = pos1 + (size_t)b * 3 * N1;
    const double qx = (double)p1b[n];
    const double qy = (double)p1b[N1 + n];
    const double qz = (double)p1b[2 * N1 + n];

    double bd[KNN];
    int    bi[KNN];
#pragma unroll
    for (int m = 0; m < KNN; ++m) { bd[m] = 1e300; bi[m] = 0; }

    for (int j = 0; j < CPART; ++j) {
        double dx = (double)px[j] - qx;
        double dy = (double)py[j] - qy;
        double dz = (double)pz[j] - qz;
        double d2 = dx * dx + dy * dy + dz * dz;
        if (d2 < bd[KNN - 1]) {
            bd[KNN - 1] = d2; bi[KNN - 1] = j;
#pragma unroll
            for (int m = KNN - 1; m > 0; --m) {
                if (bd[m] < bd[m - 1]) {
                    double td = bd[m]; bd[m] = bd[m - 1]; bd[m - 1] = td;
                    int ti = bi[m]; bi[m] = bi[m - 1]; bi[m - 1] = ti;
                }
            }
        }
    }
    size_t base = (((size_t)b * N1 + n) * NPART + part) * KNN;
#pragma unroll
    for (int m = 0; m < KNN; ++m) { dpart[base + m] = bd[m]; ipart[base + m] = jbase + bi[m]; }
}

__global__ __launch_bounds__(256) void knn_merge_kernel(const double* __restrict__ dpart,
                                                        const int* __restrict__ ipart,
                                                        int* __restrict__ idx_out) {
    const int q = blockIdx.x * 256 + threadIdx.x;
    const double* dp = dpart + (size_t)q * NPART * KNN;
    const int*    ip = ipart + (size_t)q * NPART * KNN;
    int h[4] = {0, 0, 0, 0};
#pragma unroll
    for (int m = 0; m < KNN; ++m) {
        double bd = 1e302; int bp = 0, bi = 0;
#pragma unroll
        for (int p = 0; p < 4; ++p) {
            double dv = (h[p] < KNN) ? dp[p * KNN + h[p]] : 1e302;
            if (dv < bd) { bd = dv; bp = p; bi = ip[p * KNN + h[p]]; }
        }
        idx_out[(size_t)q * KNN + m] = bi;
#pragma unroll
        for (int p = 0; p < 4; ++p) if (p == bp) h[p]++;
    }
}

// ---------------------------------------------------------------------------
// Fallback KNN (single pass, used if ws too small for partials)
// ---------------------------------------------------------------------------
__global__ __launch_bounds__(256) void knn_kernel(const float* __restrict__ pos1,
                                                  const float* __restrict__ pos2,
                                                  int* __restrict__ idx_out) {
    __shared__ float px[N2], py[N2], pz[N2];
    const int t = threadIdx.x;
    const int b = blockIdx.x / (N1 / 256);
    const int n = (blockIdx.x % (N1 / 256)) * 256 + t;
    const float* p2b = pos2 + (size_t)b * 3 * N2;
    for (int i = t; i < N2; i += 256) { px[i] = p2b[i]; py[i] = p2b[N2 + i]; pz[i] = p2b[2 * N2 + i]; }
    __syncthreads();
    const float* p1b = pos1 + (size_t)b * 3 * N1;
    const double qx = (double)p1b[n], qy = (double)p1b[N1 + n], qz = (double)p1b[2 * N1 + n];
    double bd[KNN]; int bi[KNN];
#pragma unroll
    for (int m = 0; m < KNN; ++m) { bd[m] = 1e300; bi[m] = 0; }
    for (int j = 0; j < N2; ++j) {
        double dx = (double)px[j] - qx, dy = (double)py[j] - qy, dz = (double)pz[j] - qz;
        double d2 = dx * dx + dy * dy + dz * dz;
        if (d2 < bd[KNN - 1]) {
            bd[KNN - 1] = d2; bi[KNN - 1] = j;
#pragma unroll
            for (int m = KNN - 1; m > 0; --m)
                if (bd[m] < bd[m - 1]) {
                    double td = bd[m]; bd[m] = bd[m - 1]; bd[m - 1] = td;
                    int ti = bi[m]; bi[m] = bi[m - 1]; bi[m - 1] = ti;
                }
        }
    }
    int* o = idx_out + ((size_t)b * N1 + n) * KNN;
#pragma unroll
    for (int m = 0; m < KNN; ++m) o[m] = bi[m];
}

// ---------------------------------------------------------------------------
// G0t[b][j][c] = sum_i feature2[b][i][j] * w1_0[c][i]   (fp32, point-major)
// 32j x 128c per block -> 256 blocks.
// ---------------------------------------------------------------------------
__global__ __launch_bounds__(256) void g0_kernel(const float* __restrict__ f2,
                                                 const float* __restrict__ w10,
                                                 float* __restrict__ g0t) {
    __shared__ float At[32][36];
    __shared__ float Wt[32][132];
    const int t = threadIdx.x;
    const int b = blockIdx.x >> 6;
    const int jt = (blockIdx.x & 63) * 32;
    const float* A = f2 + (size_t)b * C2 * N2;

    float acc[4][4];
#pragma unroll
    for (int r = 0; r < 4; ++r)
#pragma unroll
        for (int s = 0; s < 4; ++s) acc[r][s] = 0.f;

    const int lj = t & 31, li4 = (t >> 5) * 4;
    const int wc = t >> 1, wih = (t & 1) * 16;
    const int jg = t & 7, cg = t >> 3;

    for (int i0 = 0; i0 < C2; i0 += 32) {
        __syncthreads();
#pragma unroll
        for (int u = 0; u < 4; ++u)
            At[li4 + u][lj] = A[(size_t)(i0 + li4 + u) * N2 + jt + lj];
#pragma unroll
        for (int u = 0; u < 16; ++u)
            Wt[wih + u][wc] = w10[(size_t)wc * 515 + i0 + wih + u];
        __syncthreads();
#pragma unroll
        for (int ii = 0; ii < 32; ++ii) {
            float a[4], w[4];
            *(float4*)&a[0] = *(const float4*)&At[ii][jg * 4];
            *(float4*)&w[0] = *(const float4*)&Wt[ii][cg * 4];
#pragma unroll
            for (int r = 0; r < 4; ++r)
#pragma unroll
                for (int s = 0; s < 4; ++s) acc[r][s] += a[r] * w[s];
        }
    }
#pragma unroll
    for (int r = 0; r < 4; ++r) {
        int j = jt + jg * 4 + r;
        *(float4*)&g0t[((size_t)b * N2 + j) * 128 + cg * 4] =
            make_float4(acc[r][0], acc[r][1], acc[r][2], acc[r][3]);
    }
}

// ---------------------------------------------------------------------------
__global__ __launch_bounds__(256) void convert_weights(const float* __restrict__ w11,
                                                       const float* __restrict__ w12,
                                                       const float* __restrict__ w20,
                                                       unsigned short* __restrict__ w11b,
                                                       unsigned short* __restrict__ w12b,
                                                       unsigned short* __restrict__ w20b) {
    int i = blockIdx.x * 256 + threadIdx.x;
    if (i < 16384)  w11b[i] = f2bf(w11[i]);
    if (i < 32768)  w12b[i] = f2bf(w12[i]);
    if (i < 131072) w20b[i] = f2bf(w20[i]);
}

// ---------------------------------------------------------------------------
// Main fused kernel: 16 queries (128 neighbor-points) per block, 4 waves.
// h0 gather -> L1 (MFMA) -> L2 (MFMA) + max_k -> concat f1 -> final (MFMA).
// LDS 53.5 KB -> 3 blocks/CU.
// ---------------------------------------------------------------------------
__global__ __launch_bounds__(256, 3) void main_kernel(
    const int* __restrict__ idxbuf, const float* __restrict__ g0t,
    const float* __restrict__ pos1, const float* __restrict__ pos2,
    const float* __restrict__ feature1,
    const float* __restrict__ w10, const float* __restrict__ s10, const float* __restrict__ b10,
    const unsigned short* __restrict__ w11b, const float* __restrict__ s11, const float* __restrict__ b11,
    const unsigned short* __restrict__ w12b, const float* __restrict__ s12, const float* __restrict__ b12,
    const unsigned short* __restrict__ w20b, const float* __restrict__ s20, const float* __restrict__ b20,
    float* __restrict__ out) {

    __shared__ __align__(16) char smem[53504];
    char* sa = smem;                                   // [128][128] bf16 swz (h0 -> h1 -> out stage)
    char* sx = smem + 32768;                           // [16][512] bf16 swz (h2max | f1)
    float* swp = (float*)(smem + 49152);               // [5][128]
    float* spd = (float*)(smem + 51712);               // [128][3]
    unsigned short* sidx = (unsigned short*)(smem + 53248);  // [128]

    const int t = threadIdx.x;
    const int lane = t & 63;
    const int wv = t >> 6;
    const int l15 = lane & 15;
    const int lk = lane >> 4;
    const int b = blockIdx.x >> 9;
    const int n0 = (blockIdx.x & 511) << 4;

    if (t < 128) {
        sidx[t] = (unsigned short)idxbuf[((size_t)b * N1 + n0 + (t >> 3)) * KNN + (t & 7)];
        swp[t]       = w10[(size_t)t * 515 + 512];
        swp[128 + t] = w10[(size_t)t * 515 + 513];
        swp[256 + t] = w10[(size_t)t * 515 + 514];
        swp[384 + t] = s10[t];
        swp[512 + t] = b10[t];
    }
    __syncthreads();
    if (t < 128) {
        int j = sidx[t];
        int n = n0 + (t >> 3);
        const float* p2b = pos2 + (size_t)b * 3 * N2;
        const float* p1b = pos1 + (size_t)b * 3 * N1;
        spd[t * 3 + 0] = p2b[j] - p1b[n];
        spd[t * 3 + 1] = p2b[N2 + j] - p1b[N1 + n];
        spd[t * 3 + 2] = p2b[2 * N2 + j] - p1b[2 * N1 + n];
    }
    __syncthreads();

    // ---- Phase A: h0 = relu(bn(g0[j] + Wp*pd)) -> bf16 swz in sa ----
    {
        const int ch0 = (t & 15) * 8;
        const float* g0b = g0t + (size_t)b * N2 * 128;
#pragma unroll
        for (int it = 0; it < 8; ++it) {
            int p = it * 16 + (t >> 4);
            int j = sidx[p];
            const float* gp = g0b + (size_t)j * 128 + ch0;
            float g[8];
            *(float4*)&g[0] = *(const float4*)gp;
            *(float4*)&g[4] = *(const float4*)(gp + 4);
            float pdx = spd[p * 3], pdy = spd[p * 3 + 1], pdz = spd[p * 3 + 2];
            bf16x8 pk;
#pragma unroll
            for (int u = 0; u < 8; ++u) {
                int c = ch0 + u;
                float v = g[u] + swp[c] * pdx + swp[128 + c] * pdy + swp[256 + c] * pdz;
                v = swp[384 + c] * v + swp[512 + c];
                v = v > 0.f ? v : 0.f;
                pk[u] = (short)f2bf(v);
            }
            int byte = (p * 256 + ch0 * 2) ^ ((p & 7) << 4);
            *(bf16x8*)(sa + byte) = pk;
        }
    }
    __syncthreads();

    const f32x4 zf = {0.f, 0.f, 0.f, 0.f};

    // ---- Layer 1: M=128 N=128 K=128, wave handles 2 N-tiles ----
    {
        f32x4 acc[2][8];
#pragma unroll
        for (int m = 0; m < 8; ++m) { acc[0][m] = zf; acc[1][m] = zf; }
        const int nb = wv * 32;
#pragma unroll 2
        for (int k0 = 0; k0 < 4; ++k0) {
            bf16x8 bf0 = *(const bf16x8*)(w11b + (size_t)(nb + l15) * 128 + k0 * 32 + lk * 8);
            bf16x8 bf1 = *(const bf16x8*)(w11b + (size_t)(nb + 16 + l15) * 128 + k0 * 32 + lk * 8);
#pragma unroll
            for (int m = 0; m < 8; ++m) {
                int row = m * 16 + l15;
                int byte = (row * 256 + k0 * 64 + lk * 16) ^ ((row & 7) << 4);
                bf16x8 af = *(const bf16x8*)(sa + byte);
                acc[0][m] = __builtin_amdgcn_mfma_f32_16x16x32_bf16(af, bf0, acc[0][m], 0, 0, 0);
                acc[1][m] = __builtin_amdgcn_mfma_f32_16x16x32_bf16(af, bf1, acc[1][m], 0, 0, 0);
            }
        }
        __syncthreads();   // all waves done reading h0
#pragma unroll
        for (int nt = 0; nt < 2; ++nt) {
            int c = nb + nt * 16 + l15;
            float sc = s11[c], bi = b11[c];
#pragma unroll
            for (int m = 0; m < 8; ++m) {
#pragma unroll
                for (int r = 0; r < 4; ++r) {
                    int row = m * 16 + lk * 4 + r;
                    float v = sc * acc[nt][m][r] + bi;
                    v = v > 0.f ? v : 0.f;
                    int byte = (row * 256 + c * 2) ^ ((row & 7) << 4);
                    *(unsigned short*)(sa + byte) = f2bf(v);
                }
            }
        }
    }
    __syncthreads();

    // ---- Layer 2: M=128 N=256 K=128, two N-halves; relu+bn then max over k ----
#pragma unroll 1
    for (int h = 0; h < 2; ++h) {
        f32x4 acc2[2][8];
#pragma unroll
        for (int m = 0; m < 8; ++m) { acc2[0][m] = zf; acc2[1][m] = zf; }
        const int nb = h * 128 + wv * 32;
#pragma unroll 2
        for (int k0 = 0; k0 < 4; ++k0) {
            bf16x8 bf0 = *(const bf16x8*)(w12b + (size_t)(nb + l15) * 128 + k0 * 32 + lk * 8);
            bf16x8 bf1 = *(const bf16x8*)(w12b + (size_t)(nb + 16 + l15) * 128 + k0 * 32 + lk * 8);
#pragma unroll
            for (int m = 0; m < 8; ++m) {
                int row = m * 16 + l15;
                int byte = (row * 256 + k0 * 64 + lk * 16) ^ ((row & 7) << 4);
                bf16x8 af = *(const bf16x8*)(sa + byte);
                acc2[0][m] = __builtin_amdgcn_mfma_f32_16x16x32_bf16(af, bf0, acc2[0][m], 0, 0, 0);
                acc2[1][m] = __builtin_amdgcn_mfma_f32_16x16x32_bf16(af, bf1, acc2[1][m], 0, 0, 0);
            }
        }
#pragma unroll
        for (int nt = 0; nt < 2; ++nt) {
            int c = nb + nt * 16 + l15;
            float sc = s12[c], bi = b12[c];
#pragma unroll
            for (int m = 0; m < 8; ++m) {
                float mx = 0.f;
#pragma unroll
                for (int r = 0; r < 4; ++r) {
                    float v = sc * acc2[nt][m][r] + bi;
                    v = v > 0.f ? v : 0.f;
                    mx = fmaxf(mx, v);
                }
                mx = fmaxf(mx, __shfl_xor(mx, 16, 64));
                if (lk == 0 || lk == 2) {
                    int q = m * 2 + (lk >> 1);
                    int byte = (q * 1024 + c * 2) ^ ((q & 7) << 4);
                    *(unsigned short*)(sx + byte) = f2bf(mx);
                }
            }
        }
    }

    // ---- feature1 -> sx[:, 256:512] ----
    {
        const float* f1p = feature1 + (size_t)b * C1 * N1 + (size_t)t * N1 + n0;
        float f[16];
#pragma unroll
        for (int u = 0; u < 4; ++u) *(float4*)&f[u * 4] = *(const float4*)(f1p + u * 4);
#pragma unroll
        for (int q = 0; q < 16; ++q) {
            int byte = (q * 1024 + (256 + t) * 2) ^ ((q & 7) << 4);
            *(unsigned short*)(sx + byte) = f2bf(f[q]);
        }
    }
    __syncthreads();

    // ---- Phase D: M=16 N=256 K=512; wave handles 4 N-tiles ----
    {
        f32x4 accD[4];
#pragma unroll
        for (int j = 0; j < 4; ++j) accD[j] = zf;
#pragma unroll 4
        for (int k0 = 0; k0 < 16; ++k0) {
            int byte = (l15 * 1024 + k0 * 64 + lk * 16) ^ ((l15 & 7) << 4);
            bf16x8 af = *(const bf16x8*)(sx + byte);
            bf16x8 bfr[4];
#pragma unroll
            for (int j = 0; j < 4; ++j)
                bfr[j] = *(const bf16x8*)(w20b + (size_t)(wv * 64 + j * 16 + l15) * 512 + k0 * 32 + lk * 8);
#pragma unroll
            for (int j = 0; j < 4; ++j)
                accD[j] = __builtin_amdgcn_mfma_f32_16x16x32_bf16(af, bfr[j], accD[j], 0, 0, 0);
        }
        float* sout = (float*)sa;   // [256][20] f32 (sa free: all reads done pre-barrier)
#pragma unroll
        for (int j = 0; j < 4; ++j) {
            int c = wv * 64 + j * 16 + l15;
            float sc = s20[c], bi = b20[c];
            float4 ov;
            float v0 = sc * accD[j][0] + bi; ov.x = v0 > 0.f ? v0 : 0.f;
            float v1 = sc * accD[j][1] + bi; ov.y = v1 > 0.f ? v1 : 0.f;
            float v2 = sc * accD[j][2] + bi; ov.z = v2 > 0.f ? v2 : 0.f;
            float v3 = sc * accD[j][3] + bi; ov.w = v3 > 0.f ? v3 : 0.f;
            *(float4*)&sout[c * 20 + lk * 4] = ov;
        }
    }
    __syncthreads();

    // ---- coalesced out write: thread t = channel c, 16 consecutive n ----
    {
        const float* sout = (const float*)sa;
        float* op = out + ((size_t)b * 256 + t) * N1 + n0;
#pragma unroll
        for (int u = 0; u < 4; ++u)
            *(float4*)(op + u * 4) = *(const float4*)&sout[t * 20 + u * 4];
    }
}

// ---------------------------------------------------------------------------
extern "C" void kernel_launch(void* const* d_in, const int* in_sizes, int n_in,
                              void* d_out, int out_size, void* d_ws, size_t ws_size,
                              hipStream_t stream) {
    (void)in_sizes; (void)n_in; (void)out_size;
    const float* pos1     = (const float*)d_in[0];
    const float* pos2     = (const float*)d_in[1];
    const float* feature1 = (const float*)d_in[2];
    const float* feature2 = (const float*)d_in[3];
    const float* w10 = (const float*)d_in[4];
    const float* s10 = (const float*)d_in[5];
    const float* b10 = (const float*)d_in[6];
    const float* w11 = (const float*)d_in[7];
    const float* s11 = (const float*)d_in[8];
    const float* b11 = (const float*)d_in[9];
    const float* w12 = (const float*)d_in[10];
    const float* s12 = (const float*)d_in[11];
    const float* b12 = (const float*)d_in[12];
    const float* w20 = (const float*)d_in[13];
    const float* s20 = (const float*)d_in[14];
    const float* b20 = (const float*)d_in[15];
    float* out = (float*)d_out;

    char* ws = (char*)d_ws;
    int*    idxbuf = (int*)ws;                                   // 1 MB
    float*  g0t    = (float*)(ws + (1 << 20));                   // 4 MB
    unsigned short* w11b = (unsigned short*)(ws + (5 << 20));    // 32 KB
    unsigned short* w12b = (unsigned short*)(ws + (5 << 20) + 32768);
    unsigned short* w20b = (unsigned short*)(ws + (5 << 20) + 98304);
    double* dpart  = (double*)(ws + (6 << 20));                  // 8 MB
    int*    ipart  = (int*)(ws + (14 << 20));                    // 4 MB

    convert_weights<<<512, 256, 0, stream>>>(w11, w12, w20, w11b, w12b, w20b);
    g0_kernel<<<BB * 64, 256, 0, stream>>>(feature2, w10, g0t);

    if (ws_size >= ((size_t)18 << 20)) {
        knn_part_kernel<<<BB * 32 * NPART, 256, 0, stream>>>(pos1, pos2, dpart, ipart);
        knn_merge_kernel<<<BB * N1 / 256, 256, 0, stream>>>(dpart, ipart, idxbuf);
    } else {
        knn_kernel<<<BB * (N1 / 256), 256, 0, stream>>>(pos1, pos2, idxbuf);
    }

    main_kernel<<<BB * 512, 256, 0, stream>>>(
        idxbuf, g0t, pos1, pos2, feature1,
        w10, s10, b10, w11b, s11, b11, w12b, s12, b12, w20b, s20, b20, out);
}

// Round 3
// 229.231 us; speedup vs baseline: 7.4158x; 1.2923x over previous
//
#include <hip/hip_runtime.h>

#define BB   4
#define N1   8192
#define N2   2048
#define KNN  8
#define C1   256
#define C2   512

typedef __attribute__((ext_vector_type(8))) short bf16x8;
typedef __attribute__((ext_vector_type(4))) float f32x4;

__device__ __forceinline__ unsigned short f2bf(float x) {
    union { float f; unsigned u; } v; v.f = x;
    return (unsigned short)((v.u + 0x7fffu + ((v.u >> 16) & 1u)) >> 16);
}

// ---------------------------------------------------------------------------
// KNN v3: one wave per query. Lane scans 32 candidates (f64, exact), keeps
// all 32 keys in registers + its two smallest. 8 extraction rounds via u64
// min-butterfly; winner promotes 2nd->1st; full rescan only on a lane's 2nd
// win (E ~ 0.4/wave). Key = (f64bits & ~2047) | j  (monotone for d2>=0).
// ---------------------------------------------------------------------------
__global__ __launch_bounds__(512, 2) void knn_wave(const float* __restrict__ pos1,
                                                   const float* __restrict__ pos2,
                                                   int* __restrict__ idx_out) {
    __shared__ double px[N2], py[N2], pz[N2];
    const int t = threadIdx.x;
    const int wv = t >> 6, lane = t & 63;
    const int b = blockIdx.x >> 10;                    // 1024 blocks per batch
    const int n = ((blockIdx.x & 1023) << 3) + wv;     // 8 queries per block

    const float* p2b = pos2 + (size_t)b * 3 * N2;
    for (int i = t; i < N2; i += 512) {
        px[i] = (double)p2b[i];
        py[i] = (double)p2b[N2 + i];
        pz[i] = (double)p2b[2 * N2 + i];
    }
    __syncthreads();

    const float* p1b = pos1 + (size_t)b * 3 * N1;
    const double qx = (double)p1b[n];
    const double qy = (double)p1b[N1 + n];
    const double qz = (double)p1b[2 * N1 + n];

    const unsigned long long INFK = ~0ull;
    unsigned long long keys[32];
    unsigned long long m1 = INFK, m2 = INFK;

#pragma unroll
    for (int i = 0; i < 32; ++i) {
        const int j = i * 64 + lane;
        double dx = px[j] - qx;
        double dy = py[j] - qy;
        double dz = pz[j] - qz;
        double d2 = dx * dx + dy * dy + dz * dz;
        unsigned long long k =
            (((unsigned long long)__double_as_longlong(d2)) & ~2047ull) | (unsigned)j;
        keys[i] = k;
        bool pa = k < m1, pb = k < m2;
        m2 = pa ? m1 : (pb ? k : m2);
        m1 = pa ? k : m1;
    }

    unsigned long long win[KNN];
#pragma unroll
    for (int r = 0; r < KNN; ++r) {
        unsigned long long g = m1;
#pragma unroll
        for (int s = 32; s > 0; s >>= 1) {
            unsigned long long o = __shfl_xor(g, s, 64);
            g = (o < g) ? o : g;
        }
        win[r] = g;
        if (m1 == g) {                       // unique winner lane
            if (m2 != INFK) { m1 = m2; m2 = INFK; }
            else {
                m1 = INFK; m2 = INFK;
#pragma unroll
                for (int i = 0; i < 32; ++i) {
                    unsigned long long k = (keys[i] > g) ? keys[i] : INFK;
                    bool pa = k < m1, pb = k < m2;
                    m2 = pa ? m1 : (pb ? k : m2);
                    m1 = pa ? k : m1;
                }
            }
        }
    }

    if (lane == 0) {
        int* o = idx_out + ((size_t)b * N1 + n) * KNN;
#pragma unroll
        for (int r = 0; r < KNN; ++r) o[r] = (int)(win[r] & 2047ull);
    }
}

// ---------------------------------------------------------------------------
// G0t[b][j][c] = sum_i feature2[b][i][j] * w1_0[c][i]   (fp32, point-major)
// ---------------------------------------------------------------------------
__global__ __launch_bounds__(256) void g0_kernel(const float* __restrict__ f2,
                                                 const float* __restrict__ w10,
                                                 float* __restrict__ g0t) {
    __shared__ float At[32][36];
    __shared__ float Wt[32][132];
    const int t = threadIdx.x;
    const int b = blockIdx.x >> 6;
    const int jt = (blockIdx.x & 63) * 32;
    const float* A = f2 + (size_t)b * C2 * N2;

    float acc[4][4];
#pragma unroll
    for (int r = 0; r < 4; ++r)
#pragma unroll
        for (int s = 0; s < 4; ++s) acc[r][s] = 0.f;

    const int lj = t & 31, li4 = (t >> 5) * 4;
    const int wc = t >> 1, wih = (t & 1) * 16;
    const int jg = t & 7, cg = t >> 3;

    for (int i0 = 0; i0 < C2; i0 += 32) {
        __syncthreads();
#pragma unroll
        for (int u = 0; u < 4; ++u)
            At[li4 + u][lj] = A[(size_t)(i0 + li4 + u) * N2 + jt + lj];
#pragma unroll
        for (int u = 0; u < 16; ++u)
            Wt[wih + u][wc] = w10[(size_t)wc * 515 + i0 + wih + u];
        __syncthreads();
#pragma unroll
        for (int ii = 0; ii < 32; ++ii) {
            float a[4], w[4];
            *(float4*)&a[0] = *(const float4*)&At[ii][jg * 4];
            *(float4*)&w[0] = *(const float4*)&Wt[ii][cg * 4];
#pragma unroll
            for (int r = 0; r < 4; ++r)
#pragma unroll
                for (int s = 0; s < 4; ++s) acc[r][s] += a[r] * w[s];
        }
    }
#pragma unroll
    for (int r = 0; r < 4; ++r) {
        int j = jt + jg * 4 + r;
        *(float4*)&g0t[((size_t)b * N2 + j) * 128 + cg * 4] =
            make_float4(acc[r][0], acc[r][1], acc[r][2], acc[r][3]);
    }
}

// ---------------------------------------------------------------------------
__global__ __launch_bounds__(256) void convert_weights(const float* __restrict__ w11,
                                                       const float* __restrict__ w12,
                                                       const float* __restrict__ w20,
                                                       unsigned short* __restrict__ w11b,
                                                       unsigned short* __restrict__ w12b,
                                                       unsigned short* __restrict__ w20b) {
    int i = blockIdx.x * 256 + threadIdx.x;
    if (i < 16384)  w11b[i] = f2bf(w11[i]);
    if (i < 32768)  w12b[i] = f2bf(w12[i]);
    if (i < 131072) w20b[i] = f2bf(w20[i]);
}

// ---------------------------------------------------------------------------
// Main fused kernel: 16 queries (128 neighbor-points) per block, 4 waves.
// h0 gather -> L1 (MFMA) -> L2 (MFMA) + max_k -> concat f1 -> final (MFMA).
// ---------------------------------------------------------------------------
__global__ __launch_bounds__(256, 3) void main_kernel(
    const int* __restrict__ idxbuf, const float* __restrict__ g0t,
    const float* __restrict__ pos1, const float* __restrict__ pos2,
    const float* __restrict__ feature1,
    const float* __restrict__ w10, const float* __restrict__ s10, const float* __restrict__ b10,
    const unsigned short* __restrict__ w11b, const float* __restrict__ s11, const float* __restrict__ b11,
    const unsigned short* __restrict__ w12b, const float* __restrict__ s12, const float* __restrict__ b12,
    const unsigned short* __restrict__ w20b, const float* __restrict__ s20, const float* __restrict__ b20,
    float* __restrict__ out) {

    __shared__ __align__(16) char smem[53504];
    char* sa = smem;                                   // [128][128] bf16 swz
    char* sx = smem + 32768;                           // [16][512] bf16 swz
    float* swp = (float*)(smem + 49152);               // [5][128]
    float* spd = (float*)(smem + 51712);               // [128][3]
    unsigned short* sidx = (unsigned short*)(smem + 53248);  // [128]

    const int t = threadIdx.x;
    const int lane = t & 63;
    const int wv = t >> 6;
    const int l15 = lane & 15;
    const int lk = lane >> 4;
    const int b = blockIdx.x >> 9;
    const int n0 = (blockIdx.x & 511) << 4;

    if (t < 128) {
        sidx[t] = (unsigned short)idxbuf[((size_t)b * N1 + n0 + (t >> 3)) * KNN + (t & 7)];
        swp[t]       = w10[(size_t)t * 515 + 512];
        swp[128 + t] = w10[(size_t)t * 515 + 513];
        swp[256 + t] = w10[(size_t)t * 515 + 514];
        swp[384 + t] = s10[t];
        swp[512 + t] = b10[t];
    }
    __syncthreads();
    if (t < 128) {
        int j = sidx[t];
        int n = n0 + (t >> 3);
        const float* p2b = pos2 + (size_t)b * 3 * N2;
        const float* p1b = pos1 + (size_t)b * 3 * N1;
        spd[t * 3 + 0] = p2b[j] - p1b[n];
        spd[t * 3 + 1] = p2b[N2 + j] - p1b[N1 + n];
        spd[t * 3 + 2] = p2b[2 * N2 + j] - p1b[2 * N1 + n];
    }
    __syncthreads();

    // ---- Phase A: h0 = relu(bn(g0[j] + Wp*pd)) -> bf16 swz in sa ----
    {
        const int ch0 = (t & 15) * 8;
        const float* g0b = g0t + (size_t)b * N2 * 128;
#pragma unroll
        for (int it = 0; it < 8; ++it) {
            int p = it * 16 + (t >> 4);
            int j = sidx[p];
            const float* gp = g0b + (size_t)j * 128 + ch0;
            float g[8];
            *(float4*)&g[0] = *(const float4*)gp;
            *(float4*)&g[4] = *(const float4*)(gp + 4);
            float pdx = spd[p * 3], pdy = spd[p * 3 + 1], pdz = spd[p * 3 + 2];
            bf16x8 pk;
#pragma unroll
            for (int u = 0; u < 8; ++u) {
                int c = ch0 + u;
                float v = g[u] + swp[c] * pdx + swp[128 + c] * pdy + swp[256 + c] * pdz;
                v = swp[384 + c] * v + swp[512 + c];
                v = v > 0.f ? v : 0.f;
                pk[u] = (short)f2bf(v);
            }
            int byte = (p * 256 + ch0 * 2) ^ ((p & 7) << 4);
            *(bf16x8*)(sa + byte) = pk;
        }
    }
    __syncthreads();

    const f32x4 zf = {0.f, 0.f, 0.f, 0.f};

    // ---- Layer 1: M=128 N=128 K=128 ----
    {
        f32x4 acc[2][8];
#pragma unroll
        for (int m = 0; m < 8; ++m) { acc[0][m] = zf; acc[1][m] = zf; }
        const int nb = wv * 32;
#pragma unroll 2
        for (int k0 = 0; k0 < 4; ++k0) {
            bf16x8 bf0 = *(const bf16x8*)(w11b + (size_t)(nb + l15) * 128 + k0 * 32 + lk * 8);
            bf16x8 bf1 = *(const bf16x8*)(w11b + (size_t)(nb + 16 + l15) * 128 + k0 * 32 + lk * 8);
#pragma unroll
            for (int m = 0; m < 8; ++m) {
                int row = m * 16 + l15;
                int byte = (row * 256 + k0 * 64 + lk * 16) ^ ((row & 7) << 4);
                bf16x8 af = *(const bf16x8*)(sa + byte);
                acc[0][m] = __builtin_amdgcn_mfma_f32_16x16x32_bf16(af, bf0, acc[0][m], 0, 0, 0);
                acc[1][m] = __builtin_amdgcn_mfma_f32_16x16x32_bf16(af, bf1, acc[1][m], 0, 0, 0);
            }
        }
        __syncthreads();
#pragma unroll
        for (int nt = 0; nt < 2; ++nt) {
            int c = nb + nt * 16 + l15;
            float sc = s11[c], bi = b11[c];
#pragma unroll
            for (int m = 0; m < 8; ++m) {
#pragma unroll
                for (int r = 0; r < 4; ++r) {
                    int row = m * 16 + lk * 4 + r;
                    float v = sc * acc[nt][m][r] + bi;
                    v = v > 0.f ? v : 0.f;
                    int byte = (row * 256 + c * 2) ^ ((row & 7) << 4);
                    *(unsigned short*)(sa + byte) = f2bf(v);
                }
            }
        }
    }
    __syncthreads();

    // ---- Layer 2: M=128 N=256 K=128, two N-halves; bn/relu then max over k ----
#pragma unroll 1
    for (int h = 0; h < 2; ++h) {
        f32x4 acc2[2][8];
#pragma unroll
        for (int m = 0; m < 8; ++m) { acc2[0][m] = zf; acc2[1][m] = zf; }
        const int nb = h * 128 + wv * 32;
#pragma unroll 2
        for (int k0 = 0; k0 < 4; ++k0) {
            bf16x8 bf0 = *(const bf16x8*)(w12b + (size_t)(nb + l15) * 128 + k0 * 32 + lk * 8);
            bf16x8 bf1 = *(const bf16x8*)(w12b + (size_t)(nb + 16 + l15) * 128 + k0 * 32 + lk * 8);
#pragma unroll
            for (int m = 0; m < 8; ++m) {
                int row = m * 16 + l15;
                int byte = (row * 256 + k0 * 64 + lk * 16) ^ ((row & 7) << 4);
                bf16x8 af = *(const bf16x8*)(sa + byte);
                acc2[0][m] = __builtin_amdgcn_mfma_f32_16x16x32_bf16(af, bf0, acc2[0][m], 0, 0, 0);
                acc2[1][m] = __builtin_amdgcn_mfma_f32_16x16x32_bf16(af, bf1, acc2[1][m], 0, 0, 0);
            }
        }
#pragma unroll
        for (int nt = 0; nt < 2; ++nt) {
            int c = nb + nt * 16 + l15;
            float sc = s12[c], bi = b12[c];
#pragma unroll
            for (int m = 0; m < 8; ++m) {
                float mx = 0.f;
#pragma unroll
                for (int r = 0; r < 4; ++r) {
                    float v = sc * acc2[nt][m][r] + bi;
                    v = v > 0.f ? v : 0.f;
                    mx = fmaxf(mx, v);
                }
                mx = fmaxf(mx, __shfl_xor(mx, 16, 64));
                if (lk == 0 || lk == 2) {
                    int q = m * 2 + (lk >> 1);
                    int byte = (q * 1024 + c * 2) ^ ((q & 7) << 4);
                    *(unsigned short*)(sx + byte) = f2bf(mx);
                }
            }
        }
    }

    // ---- feature1 -> sx[:, 256:512] ----
    {
        const float* f1p = feature1 + (size_t)b * C1 * N1 + (size_t)t * N1 + n0;
        float f[16];
#pragma unroll
        for (int u = 0; u < 4; ++u) *(float4*)&f[u * 4] = *(const float4*)(f1p + u * 4);
#pragma unroll
        for (int q = 0; q < 16; ++q) {
            int byte = (q * 1024 + (256 + t) * 2) ^ ((q & 7) << 4);
            *(unsigned short*)(sx + byte) = f2bf(f[q]);
        }
    }
    __syncthreads();

    // ---- Phase D: M=16 N=256 K=512 ----
    {
        f32x4 accD[4];
#pragma unroll
        for (int j = 0; j < 4; ++j) accD[j] = zf;
#pragma unroll 4
        for (int k0 = 0; k0 < 16; ++k0) {
            int byte = (l15 * 1024 + k0 * 64 + lk * 16) ^ ((l15 & 7) << 4);
            bf16x8 af = *(const bf16x8*)(sx + byte);
            bf16x8 bfr[4];
#pragma unroll
            for (int j = 0; j < 4; ++j)
                bfr[j] = *(const bf16x8*)(w20b + (size_t)(wv * 64 + j * 16 + l15) * 512 + k0 * 32 + lk * 8);
#pragma unroll
            for (int j = 0; j < 4; ++j)
                accD[j] = __builtin_amdgcn_mfma_f32_16x16x32_bf16(af, bfr[j], accD[j], 0, 0, 0);
        }
        float* sout = (float*)sa;
#pragma unroll
        for (int j = 0; j < 4; ++j) {
            int c = wv * 64 + j * 16 + l15;
            float sc = s20[c], bi = b20[c];
            float4 ov;
            float v0 = sc * accD[j][0] + bi; ov.x = v0 > 0.f ? v0 : 0.f;
            float v1 = sc * accD[j][1] + bi; ov.y = v1 > 0.f ? v1 : 0.f;
            float v2 = sc * accD[j][2] + bi; ov.z = v2 > 0.f ? v2 : 0.f;
            float v3 = sc * accD[j][3] + bi; ov.w = v3 > 0.f ? v3 : 0.f;
            *(float4*)&sout[c * 20 + lk * 4] = ov;
        }
    }
    __syncthreads();

    {
        const float* sout = (const float*)sa;
        float* op = out + ((size_t)b * 256 + t) * N1 + n0;
#pragma unroll
        for (int u = 0; u < 4; ++u)
            *(float4*)(op + u * 4) = *(const float4*)&sout[t * 20 + u * 4];
    }
}

// ---------------------------------------------------------------------------
extern "C" void kernel_launch(void* const* d_in, const int* in_sizes, int n_in,
                              void* d_out, int out_size, void* d_ws, size_t ws_size,
                              hipStream_t stream) {
    (void)in_sizes; (void)n_in; (void)out_size; (void)ws_size;
    const float* pos1     = (const float*)d_in[0];
    const float* pos2     = (const float*)d_in[1];
    const float* feature1 = (const float*)d_in[2];
    const float* feature2 = (const float*)d_in[3];
    const float* w10 = (const float*)d_in[4];
    const float* s10 = (const float*)d_in[5];
    const float* b10 = (const float*)d_in[6];
    const float* w11 = (const float*)d_in[7];
    const float* s11 = (const float*)d_in[8];
    const float* b11 = (const float*)d_in[9];
    const float* w12 = (const float*)d_in[10];
    const float* s12 = (const float*)d_in[11];
    const float* b12 = (const float*)d_in[12];
    const float* w20 = (const float*)d_in[13];
    const float* s20 = (const float*)d_in[14];
    const float* b20 = (const float*)d_in[15];
    float* out = (float*)d_out;

    char* ws = (char*)d_ws;
    int*    idxbuf = (int*)ws;                                   // 1 MB
    float*  g0t    = (float*)(ws + (1 << 20));                   // 4 MB
    unsigned short* w11b = (unsigned short*)(ws + (5 << 20));
    unsigned short* w12b = (unsigned short*)(ws + (5 << 20) + 32768);
    unsigned short* w20b = (unsigned short*)(ws + (5 << 20) + 98304);

    convert_weights<<<512, 256, 0, stream>>>(w11, w12, w20, w11b, w12b, w20b);
    g0_kernel<<<BB * 64, 256, 0, stream>>>(feature2, w10, g0t);
    knn_wave<<<BB * 1024, 512, 0, stream>>>(pos1, pos2, idxbuf);

    main_kernel<<<BB * 512, 256, 0, stream>>>(
        idxbuf, g0t, pos1, pos2, feature1,
        w10, s10, b10, w11b, s11, b11, w12b, s12, b12, w20b, s20, b20, out);
}

// Round 4
// 210.890 us; speedup vs baseline: 8.0607x; 1.0870x over previous
//
#include <hip/hip_runtime.h>

#define BB   4
#define N1   8192
#define N2   2048
#define KNN  8
#define C1   256
#define C2   512

typedef __attribute__((ext_vector_type(8))) short bf16x8;
typedef __attribute__((ext_vector_type(4))) float f32x4;

__device__ __forceinline__ unsigned short f2bf(float x) {
    union { float f; unsigned u; } v; v.f = x;
    return (unsigned short)((v.u + 0x7fffu + ((v.u >> 16) & 1u)) >> 16);
}

// ---------------------------------------------------------------------------
// KNN: one wave per query. pos2 staged f32 in LDS (24KB), distances computed
// exact f64. Lane tracks its two smallest keys over its 32 candidates; 8
// extraction rounds via u64 min-butterfly. On a lane's 2nd win (rare, ~1.4%
// per query) the lane RECOMPUTES its 32 keys from LDS (no keys[] array ->
// ~40 VGPR -> 8 waves/SIMD). Key = (f64bits & ~2047) | j (monotone, d2>=0;
// ties break toward smaller j like lax.top_k).
// ---------------------------------------------------------------------------
__global__ __launch_bounds__(512, 8) void knn_wave(const float* __restrict__ pos1,
                                                   const float* __restrict__ pos2,
                                                   int* __restrict__ idx_out) {
    __shared__ float px[N2], py[N2], pz[N2];
    const int t = threadIdx.x;
    const int wv = t >> 6, lane = t & 63;
    const int b = blockIdx.x >> 10;
    const int n = ((blockIdx.x & 1023) << 3) + wv;

    const float* p2b = pos2 + (size_t)b * 3 * N2;
    for (int i = t; i < N2; i += 512) {
        px[i] = p2b[i];
        py[i] = p2b[N2 + i];
        pz[i] = p2b[2 * N2 + i];
    }
    __syncthreads();

    const float* p1b = pos1 + (size_t)b * 3 * N1;
    const double qx = (double)p1b[n];
    const double qy = (double)p1b[N1 + n];
    const double qz = (double)p1b[2 * N1 + n];

    const unsigned long long INFK = ~0ull;
    unsigned long long m1 = INFK, m2 = INFK;

#pragma unroll 8
    for (int i = 0; i < 32; ++i) {
        const int j = i * 64 + lane;
        double dx = (double)px[j] - qx;
        double dy = (double)py[j] - qy;
        double dz = (double)pz[j] - qz;
        double d2 = dx * dx + dy * dy + dz * dz;
        unsigned long long k =
            (((unsigned long long)__double_as_longlong(d2)) & ~2047ull) | (unsigned)j;
        bool pa = k < m1, pb = k < m2;
        m2 = pa ? m1 : (pb ? k : m2);
        m1 = pa ? k : m1;
    }

    int* o = idx_out + ((size_t)b * N1 + n) * KNN;
#pragma unroll
    for (int r = 0; r < KNN; ++r) {
        unsigned long long g = m1;
#pragma unroll
        for (int s = 32; s > 0; s >>= 1) {
            unsigned long long v = __shfl_xor(g, s, 64);
            g = (v < g) ? v : g;
        }
        if (lane == 0) o[r] = (int)(g & 2047ull);
        if (m1 == g) {
            if (m2 != INFK) { m1 = m2; m2 = INFK; }
            else {
                m1 = INFK; m2 = INFK;
                for (int i = 0; i < 32; ++i) {          // rare rescan
                    const int j = i * 64 + lane;
                    double dx = (double)px[j] - qx;
                    double dy = (double)py[j] - qy;
                    double dz = (double)pz[j] - qz;
                    double d2 = dx * dx + dy * dy + dz * dz;
                    unsigned long long k =
                        (((unsigned long long)__double_as_longlong(d2)) & ~2047ull) | (unsigned)j;
                    if (k <= g) k = INFK;
                    bool pa = k < m1, pb = k < m2;
                    m2 = pa ? m1 : (pb ? k : m2);
                    m1 = pa ? k : m1;
                }
            }
        }
    }
}

// ---------------------------------------------------------------------------
// G0t[b][j][c] = sum_i feature2[b][i][j] * w1_0[c][i]   (fp32, point-major)
// ---------------------------------------------------------------------------
__global__ __launch_bounds__(256) void g0_kernel(const float* __restrict__ f2,
                                                 const float* __restrict__ w10,
                                                 float* __restrict__ g0t) {
    __shared__ float At[32][36];
    __shared__ float Wt[32][132];
    const int t = threadIdx.x;
    const int b = blockIdx.x >> 6;
    const int jt = (blockIdx.x & 63) * 32;
    const float* A = f2 + (size_t)b * C2 * N2;

    float acc[4][4];
#pragma unroll
    for (int r = 0; r < 4; ++r)
#pragma unroll
        for (int s = 0; s < 4; ++s) acc[r][s] = 0.f;

    const int lj = t & 31, li4 = (t >> 5) * 4;
    const int wc = t >> 1, wih = (t & 1) * 16;
    const int jg = t & 7, cg = t >> 3;

    for (int i0 = 0; i0 < C2; i0 += 32) {
        __syncthreads();
#pragma unroll
        for (int u = 0; u < 4; ++u)
            At[li4 + u][lj] = A[(size_t)(i0 + li4 + u) * N2 + jt + lj];
#pragma unroll
        for (int u = 0; u < 16; ++u)
            Wt[wih + u][wc] = w10[(size_t)wc * 515 + i0 + wih + u];
        __syncthreads();
#pragma unroll
        for (int ii = 0; ii < 32; ++ii) {
            float a[4], w[4];
            *(float4*)&a[0] = *(const float4*)&At[ii][jg * 4];
            *(float4*)&w[0] = *(const float4*)&Wt[ii][cg * 4];
#pragma unroll
            for (int r = 0; r < 4; ++r)
#pragma unroll
                for (int s = 0; s < 4; ++s) acc[r][s] += a[r] * w[s];
        }
    }
#pragma unroll
    for (int r = 0; r < 4; ++r) {
        int j = jt + jg * 4 + r;
        *(float4*)&g0t[((size_t)b * N2 + j) * 128 + cg * 4] =
            make_float4(acc[r][0], acc[r][1], acc[r][2], acc[r][3]);
    }
}

// ---------------------------------------------------------------------------
__global__ __launch_bounds__(256) void convert_weights(const float* __restrict__ w11,
                                                       const float* __restrict__ w12,
                                                       const float* __restrict__ w20,
                                                       unsigned short* __restrict__ w11b,
                                                       unsigned short* __restrict__ w12b,
                                                       unsigned short* __restrict__ w20b) {
    int i = blockIdx.x * 256 + threadIdx.x;
    if (i < 16384)  w11b[i] = f2bf(w11[i]);
    if (i < 32768)  w12b[i] = f2bf(w12[i]);
    if (i < 131072) w20b[i] = f2bf(w20[i]);
}

// ---------------------------------------------------------------------------
// f1 transpose: [B][256c][8192n] f32 -> [B*N1][256] bf16, 64x64 tiles.
// ---------------------------------------------------------------------------
__global__ __launch_bounds__(256) void f1_transpose(const float* __restrict__ f1,
                                                    unsigned short* __restrict__ f1t) {
    __shared__ float tile[64][65];
    const int t = threadIdx.x;
    const int b  = blockIdx.x >> 9;
    const int c0 = ((blockIdx.x >> 7) & 3) * 64;
    const int n0 = (blockIdx.x & 127) * 64;

    {
        const int c = t >> 2, ng = (t & 3) * 16;
        const float* src = f1 + ((size_t)b * C1 + c0 + c) * N1 + n0 + ng;
#pragma unroll
        for (int u = 0; u < 4; ++u)
            *(float4*)&tile[c][ng + u * 4] = *(const float4*)(src + u * 4);
    }
    __syncthreads();
    {
        const int n = t >> 2, cg = (t & 3) * 16;
        unsigned short v[16];
#pragma unroll
        for (int u = 0; u < 16; ++u) v[u] = f2bf(tile[cg + u][n]);
        unsigned short* dst = f1t + ((size_t)b * N1 + n0 + n) * 256 + c0 + cg;
        *(bf16x8*)dst       = *(bf16x8*)&v[0];
        *(bf16x8*)(dst + 8) = *(bf16x8*)&v[8];
    }
}

// ---------------------------------------------------------------------------
// Main fused kernel: 16 queries (128 neighbor-points) per block, 4 waves.
// h0 gather -> L1 (MFMA) -> L2 (MFMA) + max_k -> pooled (bf16, global).
// LDS 36.3KB -> 4 blocks/CU.
// ---------------------------------------------------------------------------
__global__ __launch_bounds__(256, 4) void main_kernel(
    const int* __restrict__ idxbuf, const float* __restrict__ g0t,
    const float* __restrict__ pos1, const float* __restrict__ pos2,
    const float* __restrict__ w10, const float* __restrict__ s10, const float* __restrict__ b10,
    const unsigned short* __restrict__ w11b, const float* __restrict__ s11, const float* __restrict__ b11,
    const unsigned short* __restrict__ w12b, const float* __restrict__ s12, const float* __restrict__ b12,
    unsigned short* __restrict__ pooled) {

    __shared__ __align__(16) char smem[37120];
    char* sa = smem;                                         // [128][128] bf16 swz
    float* swp = (float*)(smem + 32768);                     // [5][128]
    float* spd = (float*)(smem + 35328);                     // [128][3]
    unsigned short* sidx = (unsigned short*)(smem + 36864);  // [128]

    const int t = threadIdx.x;
    const int lane = t & 63;
    const int wv = t >> 6;
    const int l15 = lane & 15;
    const int lk = lane >> 4;
    const int b = blockIdx.x >> 9;
    const int n0 = (blockIdx.x & 511) << 4;

    if (t < 128) {
        sidx[t] = (unsigned short)idxbuf[((size_t)b * N1 + n0 + (t >> 3)) * KNN + (t & 7)];
        swp[t]       = w10[(size_t)t * 515 + 512];
        swp[128 + t] = w10[(size_t)t * 515 + 513];
        swp[256 + t] = w10[(size_t)t * 515 + 514];
        swp[384 + t] = s10[t];
        swp[512 + t] = b10[t];
    }
    __syncthreads();
    if (t < 128) {
        int j = sidx[t];
        int n = n0 + (t >> 3);
        const float* p2b = pos2 + (size_t)b * 3 * N2;
        const float* p1b = pos1 + (size_t)b * 3 * N1;
        spd[t * 3 + 0] = p2b[j] - p1b[n];
        spd[t * 3 + 1] = p2b[N2 + j] - p1b[N1 + n];
        spd[t * 3 + 2] = p2b[2 * N2 + j] - p1b[2 * N1 + n];
    }
    __syncthreads();

    // ---- Phase A: h0 = relu(bn(g0[j] + Wp*pd)) -> bf16 swz in sa ----
    {
        const int ch0 = (t & 15) * 8;
        const float* g0b = g0t + (size_t)b * N2 * 128;
#pragma unroll
        for (int it = 0; it < 8; ++it) {
            int p = it * 16 + (t >> 4);
            int j = sidx[p];
            const float* gp = g0b + (size_t)j * 128 + ch0;
            float g[8];
            *(float4*)&g[0] = *(const float4*)gp;
            *(float4*)&g[4] = *(const float4*)(gp + 4);
            float pdx = spd[p * 3], pdy = spd[p * 3 + 1], pdz = spd[p * 3 + 2];
            bf16x8 pk;
#pragma unroll
            for (int u = 0; u < 8; ++u) {
                int c = ch0 + u;
                float v = g[u] + swp[c] * pdx + swp[128 + c] * pdy + swp[256 + c] * pdz;
                v = swp[384 + c] * v + swp[512 + c];
                v = v > 0.f ? v : 0.f;
                pk[u] = (short)f2bf(v);
            }
            int byte = (p * 256 + ch0 * 2) ^ ((p & 7) << 4);
            *(bf16x8*)(sa + byte) = pk;
        }
    }
    __syncthreads();

    const f32x4 zf = {0.f, 0.f, 0.f, 0.f};

    // ---- Layer 1: M=128 N=128 K=128 ----
    {
        f32x4 acc[2][8];
#pragma unroll
        for (int m = 0; m < 8; ++m) { acc[0][m] = zf; acc[1][m] = zf; }
        const int nb = wv * 32;
#pragma unroll 2
        for (int k0 = 0; k0 < 4; ++k0) {
            bf16x8 bf0 = *(const bf16x8*)(w11b + (size_t)(nb + l15) * 128 + k0 * 32 + lk * 8);
            bf16x8 bf1 = *(const bf16x8*)(w11b + (size_t)(nb + 16 + l15) * 128 + k0 * 32 + lk * 8);
#pragma unroll
            for (int m = 0; m < 8; ++m) {
                int row = m * 16 + l15;
                int byte = (row * 256 + k0 * 64 + lk * 16) ^ ((row & 7) << 4);
                bf16x8 af = *(const bf16x8*)(sa + byte);
                acc[0][m] = __builtin_amdgcn_mfma_f32_16x16x32_bf16(af, bf0, acc[0][m], 0, 0, 0);
                acc[1][m] = __builtin_amdgcn_mfma_f32_16x16x32_bf16(af, bf1, acc[1][m], 0, 0, 0);
            }
        }
        __syncthreads();   // all waves done reading h0
#pragma unroll
        for (int nt = 0; nt < 2; ++nt) {
            int c = nb + nt * 16 + l15;
            float sc = s11[c], bi = b11[c];
#pragma unroll
            for (int m = 0; m < 8; ++m) {
#pragma unroll
                for (int r = 0; r < 4; ++r) {
                    int row = m * 16 + lk * 4 + r;
                    float v = sc * acc[nt][m][r] + bi;
                    v = v > 0.f ? v : 0.f;
                    int byte = (row * 256 + c * 2) ^ ((row & 7) << 4);
                    *(unsigned short*)(sa + byte) = f2bf(v);
                }
            }
        }
    }
    __syncthreads();

    // ---- Layer 2: M=128 N=256 K=128; bn/relu, max over k, write pooled ----
    unsigned short* pb = pooled + ((size_t)b * N1 + n0) * 256;
#pragma unroll 1
    for (int h = 0; h < 2; ++h) {
        f32x4 acc2[2][8];
#pragma unroll
        for (int m = 0; m < 8; ++m) { acc2[0][m] = zf; acc2[1][m] = zf; }
        const int nb = h * 128 + wv * 32;
#pragma unroll 2
        for (int k0 = 0; k0 < 4; ++k0) {
            bf16x8 bf0 = *(const bf16x8*)(w12b + (size_t)(nb + l15) * 128 + k0 * 32 + lk * 8);
            bf16x8 bf1 = *(const bf16x8*)(w12b + (size_t)(nb + 16 + l15) * 128 + k0 * 32 + lk * 8);
#pragma unroll
            for (int m = 0; m < 8; ++m) {
                int row = m * 16 + l15;
                int byte = (row * 256 + k0 * 64 + lk * 16) ^ ((row & 7) << 4);
                bf16x8 af = *(const bf16x8*)(sa + byte);
                acc2[0][m] = __builtin_amdgcn_mfma_f32_16x16x32_bf16(af, bf0, acc2[0][m], 0, 0, 0);
                acc2[1][m] = __builtin_amdgcn_mfma_f32_16x16x32_bf16(af, bf1, acc2[1][m], 0, 0, 0);
            }
        }
#pragma unroll
        for (int nt = 0; nt < 2; ++nt) {
            int c = nb + nt * 16 + l15;
            float sc = s12[c], bi = b12[c];
#pragma unroll
            for (int m = 0; m < 8; ++m) {
                float mx = 0.f;
#pragma unroll
                for (int r = 0; r < 4; ++r) {
                    float v = sc * acc2[nt][m][r] + bi;
                    v = v > 0.f ? v : 0.f;
                    mx = fmaxf(mx, v);
                }
                mx = fmaxf(mx, __shfl_xor(mx, 16, 64));
                if ((lk & 1) == 0) {
                    int q = m * 2 + (lk >> 1);
                    pb[(size_t)q * 256 + c] = f2bf(mx);
                }
            }
        }
    }
}

// ---------------------------------------------------------------------------
// Final layer: out[b][o][n] = relu(s*(W20 . [pooled|f1t]) + b)
// Block: M=64 queries, N=256 outputs, K=512; 4 waves (each 64 o-cols).
// ---------------------------------------------------------------------------
__global__ __launch_bounds__(256, 4) void final_kernel(
    const unsigned short* __restrict__ pooled,
    const unsigned short* __restrict__ f1t,
    const unsigned short* __restrict__ w20b,
    const float* __restrict__ s20, const float* __restrict__ b20,
    float* __restrict__ out) {

    __shared__ __align__(16) char sA[16384];   // [64][128] bf16 swz
    const int t = threadIdx.x;
    const int lane = t & 63;
    const int wv = t >> 6;
    const int l15 = lane & 15;
    const int lk = lane >> 4;
    const int n0g = blockIdx.x * 64;
    const int b = n0g >> 13;
    const int n0 = n0g & (N1 - 1);
    const int obase = wv * 64;

    f32x4 acc[4][4];
    const f32x4 zf = {0.f, 0.f, 0.f, 0.f};
#pragma unroll
    for (int m = 0; m < 4; ++m)
#pragma unroll
        for (int ot = 0; ot < 4; ++ot) acc[m][ot] = zf;

#pragma unroll 1
    for (int chunk = 0; chunk < 4; ++chunk) {
        const unsigned short* src = (chunk < 2) ? pooled : f1t;
        const int kc = (chunk & 1) * 128;
        __syncthreads();
        {
            const int row = t >> 2, seg = t & 3;
            const unsigned short* sp = src + ((size_t)n0g + row) * 256 + kc + seg * 32;
            bf16x8 v0 = *(const bf16x8*)sp;
            bf16x8 v1 = *(const bf16x8*)(sp + 8);
            bf16x8 v2 = *(const bf16x8*)(sp + 16);
            bf16x8 v3 = *(const bf16x8*)(sp + 24);
            const int base = row * 256 + seg * 64;
            const int x = (row & 7) << 4;
            *(bf16x8*)(sA + ((base)      ^ x)) = v0;
            *(bf16x8*)(sA + ((base + 16) ^ x)) = v1;
            *(bf16x8*)(sA + ((base + 32) ^ x)) = v2;
            *(bf16x8*)(sA + ((base + 48) ^ x)) = v3;
        }
        __syncthreads();
        const int kg = chunk * 128;
#pragma unroll
        for (int k0 = 0; k0 < 4; ++k0) {
            bf16x8 bfr[4];
#pragma unroll
            for (int ot = 0; ot < 4; ++ot)
                bfr[ot] = *(const bf16x8*)(w20b + (size_t)(obase + ot * 16 + l15) * 512 + kg + k0 * 32 + lk * 8);
#pragma unroll
            for (int m = 0; m < 4; ++m) {
                int row = m * 16 + l15;
                bf16x8 af = *(const bf16x8*)(sA + ((row * 256 + k0 * 64 + lk * 16) ^ ((row & 7) << 4)));
#pragma unroll
                for (int ot = 0; ot < 4; ++ot)
                    acc[m][ot] = __builtin_amdgcn_mfma_f32_16x16x32_bf16(af, bfr[ot], acc[m][ot], 0, 0, 0);
            }
        }
    }

#pragma unroll
    for (int ot = 0; ot < 4; ++ot) {
        int o = obase + ot * 16 + l15;
        float sc = s20[o], bi = b20[o];
#pragma unroll
        for (int m = 0; m < 4; ++m) {
            float4 ov;
            float v0 = sc * acc[m][ot][0] + bi; ov.x = v0 > 0.f ? v0 : 0.f;
            float v1 = sc * acc[m][ot][1] + bi; ov.y = v1 > 0.f ? v1 : 0.f;
            float v2 = sc * acc[m][ot][2] + bi; ov.z = v2 > 0.f ? v2 : 0.f;
            float v3 = sc * acc[m][ot][3] + bi; ov.w = v3 > 0.f ? v3 : 0.f;
            *(float4*)(out + ((size_t)b * 256 + o) * N1 + n0 + m * 16 + lk * 4) = ov;
        }
    }
}

// ---------------------------------------------------------------------------
extern "C" void kernel_launch(void* const* d_in, const int* in_sizes, int n_in,
                              void* d_out, int out_size, void* d_ws, size_t ws_size,
                              hipStream_t stream) {
    (void)in_sizes; (void)n_in; (void)out_size; (void)ws_size;
    const float* pos1     = (const float*)d_in[0];
    const float* pos2     = (const float*)d_in[1];
    const float* feature1 = (const float*)d_in[2];
    const float* feature2 = (const float*)d_in[3];
    const float* w10 = (const float*)d_in[4];
    const float* s10 = (const float*)d_in[5];
    const float* b10 = (const float*)d_in[6];
    const float* w11 = (const float*)d_in[7];
    const float* s11 = (const float*)d_in[8];
    const float* b11 = (const float*)d_in[9];
    const float* w12 = (const float*)d_in[10];
    const float* s12 = (const float*)d_in[11];
    const float* b12 = (const float*)d_in[12];
    const float* w20 = (const float*)d_in[13];
    const float* s20 = (const float*)d_in[14];
    const float* b20 = (const float*)d_in[15];
    float* out = (float*)d_out;

    char* ws = (char*)d_ws;
    int*    idxbuf = (int*)ws;                                   // @0    : 1 MB
    float*  g0t    = (float*)(ws + (1 << 20));                   // @1 MB : 4 MB
    unsigned short* w11b = (unsigned short*)(ws + (5 << 20));    // @5 MB : 32 KB
    unsigned short* w12b = (unsigned short*)(ws + (5 << 20) + 32768);   // 64 KB
    unsigned short* w20b = (unsigned short*)(ws + (5 << 20) + 98304);   // 256 KB
    unsigned short* pooled = (unsigned short*)(ws + (6 << 20));  // @6 MB : 16 MB
    unsigned short* f1t    = (unsigned short*)(ws + (22 << 20)); // @22 MB: 16 MB

    convert_weights<<<512, 256, 0, stream>>>(w11, w12, w20, w11b, w12b, w20b);
    f1_transpose<<<BB * 4 * 128, 256, 0, stream>>>(feature1, f1t);
    g0_kernel<<<BB * 64, 256, 0, stream>>>(feature2, w10, g0t);
    knn_wave<<<BB * 1024, 512, 0, stream>>>(pos1, pos2, idxbuf);

    main_kernel<<<BB * 512, 256, 0, stream>>>(
        idxbuf, g0t, pos1, pos2,
        w10, s10, b10, w11b, s11, b11, w12b, s12, b12, pooled);

    final_kernel<<<(BB * N1) / 64, 256, 0, stream>>>(pooled, f1t, w20b, s20, b20, out);
}

// Round 5
// 210.178 us; speedup vs baseline: 8.0880x; 1.0034x over previous
//
#include <hip/hip_runtime.h>

#define BB   4
#define N1   8192
#define N2   2048
#define KNN  8
#define C1   256
#define C2   512

typedef __attribute__((ext_vector_type(8))) short bf16x8;
typedef __attribute__((ext_vector_type(4))) float f32x4;

// hardware f32->bf16 (RNE) via native __bf16 cast (v_cvt_pk_bf16_f32 on gfx950)
__device__ __forceinline__ unsigned short f2bf(float x) {
    __bf16 h = (__bf16)x;
    union { __bf16 b; unsigned short u; } v; v.b = h;
    return v.u;
}

// ---------------------------------------------------------------------------
// KNN v4: one wave per query. f32 scan with u32 keys (bits&~0x7FF | j), lane
// tracks its 3 smallest via a min/max insert network. 8 extraction rounds of
// u32 min-butterfly + one extra for the 9th. Certification: if the quantized
// d2-field of the 9th strictly exceeds the 8th's, the f32 top-8 SET provably
// equals the exact-f64 top-8 SET (gap >= 2^-12 rel >> f32 error 2^-21; output
// is max-over-k so only the set matters). Uncertified waves (~1 in 32k)
// fall back to the exact f64 path and overwrite.
// ---------------------------------------------------------------------------
__global__ __launch_bounds__(512, 8) void knn_wave(const float* __restrict__ pos1,
                                                   const float* __restrict__ pos2,
                                                   int* __restrict__ idx_out) {
    __shared__ float pbuf[3 * N2];
    float* px = pbuf;
    float* py = pbuf + N2;
    float* pz = pbuf + 2 * N2;
    const int t = threadIdx.x;
    const int wv = t >> 6, lane = t & 63;
    const int b = blockIdx.x >> 10;
    const int n = ((blockIdx.x & 1023) << 3) + wv;

    const float* p2b = pos2 + (size_t)b * 3 * N2;
    for (int i = t; i < 3 * N2; i += 512) pbuf[i] = p2b[i];
    __syncthreads();

    const float* p1b = pos1 + (size_t)b * 3 * N1;
    const float qx = p1b[n], qy = p1b[N1 + n], qz = p1b[2 * N1 + n];

    const unsigned INF32 = 0xFFFFFFFFu;
    unsigned m1 = INF32, m2 = INF32, m3 = INF32;

#pragma unroll
    for (int i = 0; i < 32; ++i) {
        const int j = i * 64 + lane;
        float dx = px[j] - qx, dy = py[j] - qy, dz = pz[j] - qz;
        float d2 = fmaf(dx, dx, fmaf(dy, dy, dz * dz));
        unsigned k = (__float_as_uint(d2) & 0xFFFFF800u) | (unsigned)j;
        unsigned t1 = m1 < k ? m1 : k;
        unsigned t2 = m1 < k ? k : m1;
        unsigned u2 = m2 < t2 ? m2 : t2;
        unsigned u3 = m2 < t2 ? t2 : m2;
        m3 = m3 < u3 ? m3 : u3;
        m1 = t1; m2 = u2;
    }

    int* o = idx_out + ((size_t)b * N1 + n) * KNN;
    unsigned prev = 0;
#pragma unroll 1
    for (int r = 0; r < KNN; ++r) {
        unsigned g = m1;
#pragma unroll
        for (int s = 32; s; s >>= 1) {
            unsigned v = (unsigned)__shfl_xor((int)g, s, 64);
            g = v < g ? v : g;
        }
        if (lane == 0) o[r] = (int)(g & 0x7FFu);
        prev = g;
        bool w = (m1 == g);
        m1 = w ? m2 : m1;
        m2 = w ? m3 : m2;
        m3 = w ? INF32 : m3;
        if (m1 == INF32) {                       // tracked set exhausted (rare)
            unsigned a1 = INF32, a2 = INF32, a3 = INF32;
            for (int i = 0; i < 32; ++i) {
                const int j = i * 64 + lane;
                float dx = px[j] - qx, dy = py[j] - qy, dz = pz[j] - qz;
                float d2 = fmaf(dx, dx, fmaf(dy, dy, dz * dz));
                unsigned k = (__float_as_uint(d2) & 0xFFFFF800u) | (unsigned)j;
                if (k <= g) k = INF32;           // already extracted
                unsigned t1 = a1 < k ? a1 : k;
                unsigned t2 = a1 < k ? k : a1;
                unsigned u2 = a2 < t2 ? a2 : t2;
                unsigned u3 = a2 < t2 ? t2 : a2;
                a3 = a3 < u3 ? a3 : u3;
                a1 = t1; a2 = u2;
            }
            m1 = a1; m2 = a2; m3 = a3;
        }
    }
    unsigned g9 = m1;
#pragma unroll
    for (int s = 32; s; s >>= 1) {
        unsigned v = (unsigned)__shfl_xor((int)g9, s, 64);
        g9 = v < g9 ? v : g9;
    }
    if ((g9 & 0xFFFFF800u) != (prev & 0xFFFFF800u))
        return;                                   // certified (wave-uniform)

    // ---- exact f64 fallback (wave-uniform, ~1 wave per 32k) ----
    {
        const double qxd = (double)qx, qyd = (double)qy, qzd = (double)qz;
        const unsigned long long INF64 = ~0ull;
        unsigned long long M1 = INF64, M2 = INF64;
#pragma unroll 8
        for (int i = 0; i < 32; ++i) {
            const int j = i * 64 + lane;
            double dx = (double)px[j] - qxd;
            double dy = (double)py[j] - qyd;
            double dz = (double)pz[j] - qzd;
            double d2 = dx * dx + dy * dy + dz * dz;
            unsigned long long k =
                (((unsigned long long)__double_as_longlong(d2)) & ~2047ull) | (unsigned)j;
            bool pa = k < M1, pb = k < M2;
            M2 = pa ? M1 : (pb ? k : M2);
            M1 = pa ? k : M1;
        }
#pragma unroll 1
        for (int r = 0; r < KNN; ++r) {
            unsigned long long g = M1;
#pragma unroll
            for (int s = 32; s; s >>= 1) {
                unsigned long long v = __shfl_xor(g, s, 64);
                g = v < g ? v : g;
            }
            if (lane == 0) o[r] = (int)(g & 2047ull);
            if (M1 == g) {
                if (M2 != INF64) { M1 = M2; M2 = INF64; }
                else {
                    M1 = INF64; M2 = INF64;
                    for (int i = 0; i < 32; ++i) {
                        const int j = i * 64 + lane;
                        double dx = (double)px[j] - qxd;
                        double dy = (double)py[j] - qyd;
                        double dz = (double)pz[j] - qzd;
                        double d2 = dx * dx + dy * dy + dz * dz;
                        unsigned long long k =
                            (((unsigned long long)__double_as_longlong(d2)) & ~2047ull) | (unsigned)j;
                        if (k <= g) k = INF64;
                        bool pa = k < M1, pb = k < M2;
                        M2 = pa ? M1 : (pb ? k : M2);
                        M1 = pa ? k : M1;
                    }
                }
            }
        }
    }
}

// ---------------------------------------------------------------------------
// G0t[b][j][c] = sum_i feature2[b][i][j] * w1_0[c][i]   (fp32, point-major)
// ---------------------------------------------------------------------------
__global__ __launch_bounds__(256) void g0_kernel(const float* __restrict__ f2,
                                                 const float* __restrict__ w10,
                                                 float* __restrict__ g0t) {
    __shared__ float At[32][36];
    __shared__ float Wt[32][132];
    const int t = threadIdx.x;
    const int b = blockIdx.x >> 6;
    const int jt = (blockIdx.x & 63) * 32;
    const float* A = f2 + (size_t)b * C2 * N2;

    float acc[4][4];
#pragma unroll
    for (int r = 0; r < 4; ++r)
#pragma unroll
        for (int s = 0; s < 4; ++s) acc[r][s] = 0.f;

    const int lj = t & 31, li4 = (t >> 5) * 4;
    const int wc = t >> 1, wih = (t & 1) * 16;
    const int jg = t & 7, cg = t >> 3;

    for (int i0 = 0; i0 < C2; i0 += 32) {
        __syncthreads();
#pragma unroll
        for (int u = 0; u < 4; ++u)
            At[li4 + u][lj] = A[(size_t)(i0 + li4 + u) * N2 + jt + lj];
#pragma unroll
        for (int u = 0; u < 16; ++u)
            Wt[wih + u][wc] = w10[(size_t)wc * 515 + i0 + wih + u];
        __syncthreads();
#pragma unroll
        for (int ii = 0; ii < 32; ++ii) {
            float a[4], w[4];
            *(float4*)&a[0] = *(const float4*)&At[ii][jg * 4];
            *(float4*)&w[0] = *(const float4*)&Wt[ii][cg * 4];
#pragma unroll
            for (int r = 0; r < 4; ++r)
#pragma unroll
                for (int s = 0; s < 4; ++s) acc[r][s] += a[r] * w[s];
        }
    }
#pragma unroll
    for (int r = 0; r < 4; ++r) {
        int j = jt + jg * 4 + r;
        *(float4*)&g0t[((size_t)b * N2 + j) * 128 + cg * 4] =
            make_float4(acc[r][0], acc[r][1], acc[r][2], acc[r][3]);
    }
}

// ---------------------------------------------------------------------------
__global__ __launch_bounds__(256) void convert_weights(const float* __restrict__ w11,
                                                       const float* __restrict__ w12,
                                                       const float* __restrict__ w20,
                                                       unsigned short* __restrict__ w11b,
                                                       unsigned short* __restrict__ w12b,
                                                       unsigned short* __restrict__ w20b) {
    int i = blockIdx.x * 256 + threadIdx.x;
    if (i < 16384)  w11b[i] = f2bf(w11[i]);
    if (i < 32768)  w12b[i] = f2bf(w12[i]);
    if (i < 131072) w20b[i] = f2bf(w20[i]);
}

// ---------------------------------------------------------------------------
// f1 transpose: [B][256c][8192n] f32 -> [B*N1][256] bf16, 64x64 tiles.
// ---------------------------------------------------------------------------
__global__ __launch_bounds__(256) void f1_transpose(const float* __restrict__ f1,
                                                    unsigned short* __restrict__ f1t) {
    __shared__ float tile[64][65];
    const int t = threadIdx.x;
    const int b  = blockIdx.x >> 9;
    const int c0 = ((blockIdx.x >> 7) & 3) * 64;
    const int n0 = (blockIdx.x & 127) * 64;

    {
        const int c = t >> 2, ng = (t & 3) * 16;
        const float* src = f1 + ((size_t)b * C1 + c0 + c) * N1 + n0 + ng;
#pragma unroll
        for (int u = 0; u < 4; ++u)
            *(float4*)&tile[c][ng + u * 4] = *(const float4*)(src + u * 4);
    }
    __syncthreads();
    {
        const int n = t >> 2, cg = (t & 3) * 16;
        unsigned short v[16];
#pragma unroll
        for (int u = 0; u < 16; ++u) v[u] = f2bf(tile[cg + u][n]);
        unsigned short* dst = f1t + ((size_t)b * N1 + n0 + n) * 256 + c0 + cg;
        *(bf16x8*)dst       = *(bf16x8*)&v[0];
        *(bf16x8*)(dst + 8) = *(bf16x8*)&v[8];
    }
}

// ---------------------------------------------------------------------------
// Main fused kernel: 16 queries (128 neighbor-points) per block, 4 waves.
// h0 gather -> L1 (MFMA) -> L2 (MFMA) + max_k -> pooled (bf16, global).
// ---------------------------------------------------------------------------
__global__ __launch_bounds__(256, 4) void main_kernel(
    const int* __restrict__ idxbuf, const float* __restrict__ g0t,
    const float* __restrict__ pos1, const float* __restrict__ pos2,
    const float* __restrict__ w10, const float* __restrict__ s10, const float* __restrict__ b10,
    const unsigned short* __restrict__ w11b, const float* __restrict__ s11, const float* __restrict__ b11,
    const unsigned short* __restrict__ w12b, const float* __restrict__ s12, const float* __restrict__ b12,
    unsigned short* __restrict__ pooled) {

    __shared__ __align__(16) char smem[37120];
    char* sa = smem;                                         // [128][128] bf16 swz
    float* swp = (float*)(smem + 32768);                     // [5][128]
    float* spd = (float*)(smem + 35328);                     // [128][3]
    unsigned short* sidx = (unsigned short*)(smem + 36864);  // [128]

    const int t = threadIdx.x;
    const int lane = t & 63;
    const int wv = t >> 6;
    const int l15 = lane & 15;
    const int lk = lane >> 4;
    const int b = blockIdx.x >> 9;
    const int n0 = (blockIdx.x & 511) << 4;

    if (t < 128) {
        sidx[t] = (unsigned short)idxbuf[((size_t)b * N1 + n0 + (t >> 3)) * KNN + (t & 7)];
        swp[t]       = w10[(size_t)t * 515 + 512];
        swp[128 + t] = w10[(size_t)t * 515 + 513];
        swp[256 + t] = w10[(size_t)t * 515 + 514];
        swp[384 + t] = s10[t];
        swp[512 + t] = b10[t];
    }
    __syncthreads();
    if (t < 128) {
        int j = sidx[t];
        int n = n0 + (t >> 3);
        const float* p2b = pos2 + (size_t)b * 3 * N2;
        const float* p1b = pos1 + (size_t)b * 3 * N1;
        spd[t * 3 + 0] = p2b[j] - p1b[n];
        spd[t * 3 + 1] = p2b[N2 + j] - p1b[N1 + n];
        spd[t * 3 + 2] = p2b[2 * N2 + j] - p1b[2 * N1 + n];
    }
    __syncthreads();

    // ---- Phase A: h0 = relu(bn(g0[j] + Wp*pd)) -> bf16 swz in sa ----
    {
        const int ch0 = (t & 15) * 8;
        const float* g0b = g0t + (size_t)b * N2 * 128;
#pragma unroll
        for (int it = 0; it < 8; ++it) {
            int p = it * 16 + (t >> 4);
            int j = sidx[p];
            const float* gp = g0b + (size_t)j * 128 + ch0;
            float g[8];
            *(float4*)&g[0] = *(const float4*)gp;
            *(float4*)&g[4] = *(const float4*)(gp + 4);
            float pdx = spd[p * 3], pdy = spd[p * 3 + 1], pdz = spd[p * 3 + 2];
            bf16x8 pk;
#pragma unroll
            for (int u = 0; u < 8; ++u) {
                int c = ch0 + u;
                float v = g[u] + swp[c] * pdx + swp[128 + c] * pdy + swp[256 + c] * pdz;
                v = swp[384 + c] * v + swp[512 + c];
                v = v > 0.f ? v : 0.f;
                pk[u] = (short)f2bf(v);
            }
            int byte = (p * 256 + ch0 * 2) ^ ((p & 7) << 4);
            *(bf16x8*)(sa + byte) = pk;
        }
    }
    __syncthreads();

    const f32x4 zf = {0.f, 0.f, 0.f, 0.f};

    // ---- Layer 1: M=128 N=128 K=128 ----
    {
        f32x4 acc[2][8];
#pragma unroll
        for (int m = 0; m < 8; ++m) { acc[0][m] = zf; acc[1][m] = zf; }
        const int nb = wv * 32;
#pragma unroll 2
        for (int k0 = 0; k0 < 4; ++k0) {
            bf16x8 bf0 = *(const bf16x8*)(w11b + (size_t)(nb + l15) * 128 + k0 * 32 + lk * 8);
            bf16x8 bf1 = *(const bf16x8*)(w11b + (size_t)(nb + 16 + l15) * 128 + k0 * 32 + lk * 8);
#pragma unroll
            for (int m = 0; m < 8; ++m) {
                int row = m * 16 + l15;
                int byte = (row * 256 + k0 * 64 + lk * 16) ^ ((row & 7) << 4);
                bf16x8 af = *(const bf16x8*)(sa + byte);
                acc[0][m] = __builtin_amdgcn_mfma_f32_16x16x32_bf16(af, bf0, acc[0][m], 0, 0, 0);
                acc[1][m] = __builtin_amdgcn_mfma_f32_16x16x32_bf16(af, bf1, acc[1][m], 0, 0, 0);
            }
        }
        __syncthreads();   // all waves done reading h0
#pragma unroll
        for (int nt = 0; nt < 2; ++nt) {
            int c = nb + nt * 16 + l15;
            float sc = s11[c], bi = b11[c];
#pragma unroll
            for (int m = 0; m < 8; ++m) {
#pragma unroll
                for (int r = 0; r < 4; ++r) {
                    int row = m * 16 + lk * 4 + r;
                    float v = sc * acc[nt][m][r] + bi;
                    v = v > 0.f ? v : 0.f;
                    int byte = (row * 256 + c * 2) ^ ((row & 7) << 4);
                    *(unsigned short*)(sa + byte) = f2bf(v);
                }
            }
        }
    }
    __syncthreads();

    // ---- Layer 2: M=128 N=256 K=128; bn/relu, max over k, write pooled ----
    unsigned short* pb = pooled + ((size_t)b * N1 + n0) * 256;
#pragma unroll 1
    for (int h = 0; h < 2; ++h) {
        f32x4 acc2[2][8];
#pragma unroll
        for (int m = 0; m < 8; ++m) { acc2[0][m] = zf; acc2[1][m] = zf; }
        const int nb = h * 128 + wv * 32;
#pragma unroll 2
        for (int k0 = 0; k0 < 4; ++k0) {
            bf16x8 bf0 = *(const bf16x8*)(w12b + (size_t)(nb + l15) * 128 + k0 * 32 + lk * 8);
            bf16x8 bf1 = *(const bf16x8*)(w12b + (size_t)(nb + 16 + l15) * 128 + k0 * 32 + lk * 8);
#pragma unroll
            for (int m = 0; m < 8; ++m) {
                int row = m * 16 + l15;
                int byte = (row * 256 + k0 * 64 + lk * 16) ^ ((row & 7) << 4);
                bf16x8 af = *(const bf16x8*)(sa + byte);
                acc2[0][m] = __builtin_amdgcn_mfma_f32_16x16x32_bf16(af, bf0, acc2[0][m], 0, 0, 0);
                acc2[1][m] = __builtin_amdgcn_mfma_f32_16x16x32_bf16(af, bf1, acc2[1][m], 0, 0, 0);
            }
        }
#pragma unroll
        for (int nt = 0; nt < 2; ++nt) {
            int c = nb + nt * 16 + l15;
            float sc = s12[c], bi = b12[c];
#pragma unroll
            for (int m = 0; m < 8; ++m) {
                float mx = 0.f;
#pragma unroll
                for (int r = 0; r < 4; ++r) {
                    float v = sc * acc2[nt][m][r] + bi;
                    v = v > 0.f ? v : 0.f;
                    mx = fmaxf(mx, v);
                }
                mx = fmaxf(mx, __shfl_xor(mx, 16, 64));
                if ((lk & 1) == 0) {
                    int q = m * 2 + (lk >> 1);
                    pb[(size_t)q * 256 + c] = f2bf(mx);
                }
            }
        }
    }
}

// ---------------------------------------------------------------------------
// Final layer: out[b][o][n] = relu(s*(W20 . [pooled|f1t]) + b)
// ---------------------------------------------------------------------------
__global__ __launch_bounds__(256, 4) void final_kernel(
    const unsigned short* __restrict__ pooled,
    const unsigned short* __restrict__ f1t,
    const unsigned short* __restrict__ w20b,
    const float* __restrict__ s20, const float* __restrict__ b20,
    float* __restrict__ out) {

    __shared__ __align__(16) char sA[16384];   // [64][128] bf16 swz
    const int t = threadIdx.x;
    const int lane = t & 63;
    const int wv = t >> 6;
    const int l15 = lane & 15;
    const int lk = lane >> 4;
    const int n0g = blockIdx.x * 64;
    const int b = n0g >> 13;
    const int n0 = n0g & (N1 - 1);
    const int obase = wv * 64;

    f32x4 acc[4][4];
    const f32x4 zf = {0.f, 0.f, 0.f, 0.f};
#pragma unroll
    for (int m = 0; m < 4; ++m)
#pragma unroll
        for (int ot = 0; ot < 4; ++ot) acc[m][ot] = zf;

#pragma unroll 1
    for (int chunk = 0; chunk < 4; ++chunk) {
        const unsigned short* src = (chunk < 2) ? pooled : f1t;
        const int kc = (chunk & 1) * 128;
        __syncthreads();
        {
            const int row = t >> 2, seg = t & 3;
            const unsigned short* sp = src + ((size_t)n0g + row) * 256 + kc + seg * 32;
            bf16x8 v0 = *(const bf16x8*)sp;
            bf16x8 v1 = *(const bf16x8*)(sp + 8);
            bf16x8 v2 = *(const bf16x8*)(sp + 16);
            bf16x8 v3 = *(const bf16x8*)(sp + 24);
            const int base = row * 256 + seg * 64;
            const int x = (row & 7) << 4;
            *(bf16x8*)(sA + ((base)      ^ x)) = v0;
            *(bf16x8*)(sA + ((base + 16) ^ x)) = v1;
            *(bf16x8*)(sA + ((base + 32) ^ x)) = v2;
            *(bf16x8*)(sA + ((base + 48) ^ x)) = v3;
        }
        __syncthreads();
        const int kg = chunk * 128;
#pragma unroll
        for (int k0 = 0; k0 < 4; ++k0) {
            bf16x8 bfr[4];
#pragma unroll
            for (int ot = 0; ot < 4; ++ot)
                bfr[ot] = *(const bf16x8*)(w20b + (size_t)(obase + ot * 16 + l15) * 512 + kg + k0 * 32 + lk * 8);
#pragma unroll
            for (int m = 0; m < 4; ++m) {
                int row = m * 16 + l15;
                bf16x8 af = *(const bf16x8*)(sA + ((row * 256 + k0 * 64 + lk * 16) ^ ((row & 7) << 4)));
#pragma unroll
                for (int ot = 0; ot < 4; ++ot)
                    acc[m][ot] = __builtin_amdgcn_mfma_f32_16x16x32_bf16(af, bfr[ot], acc[m][ot], 0, 0, 0);
            }
        }
    }

#pragma unroll
    for (int ot = 0; ot < 4; ++ot) {
        int o = obase + ot * 16 + l15;
        float sc = s20[o], bi = b20[o];
#pragma unroll
        for (int m = 0; m < 4; ++m) {
            float4 ov;
            float v0 = sc * acc[m][ot][0] + bi; ov.x = v0 > 0.f ? v0 : 0.f;
            float v1 = sc * acc[m][ot][1] + bi; ov.y = v1 > 0.f ? v1 : 0.f;
            float v2 = sc * acc[m][ot][2] + bi; ov.z = v2 > 0.f ? v2 : 0.f;
            float v3 = sc * acc[m][ot][3] + bi; ov.w = v3 > 0.f ? v3 : 0.f;
            *(float4*)(out + ((size_t)b * 256 + o) * N1 + n0 + m * 16 + lk * 4) = ov;
        }
    }
}

// ---------------------------------------------------------------------------
extern "C" void kernel_launch(void* const* d_in, const int* in_sizes, int n_in,
                              void* d_out, int out_size, void* d_ws, size_t ws_size,
                              hipStream_t stream) {
    (void)in_sizes; (void)n_in; (void)out_size; (void)ws_size;
    const float* pos1     = (const float*)d_in[0];
    const float* pos2     = (const float*)d_in[1];
    const float* feature1 = (const float*)d_in[2];
    const float* feature2 = (const float*)d_in[3];
    const float* w10 = (const float*)d_in[4];
    const float* s10 = (const float*)d_in[5];
    const float* b10 = (const float*)d_in[6];
    const float* w11 = (const float*)d_in[7];
    const float* s11 = (const float*)d_in[8];
    const float* b11 = (const float*)d_in[9];
    const float* w12 = (const float*)d_in[10];
    const float* s12 = (const float*)d_in[11];
    const float* b12 = (const float*)d_in[12];
    const float* w20 = (const float*)d_in[13];
    const float* s20 = (const float*)d_in[14];
    const float* b20 = (const float*)d_in[15];
    float* out = (float*)d_out;

    char* ws = (char*)d_ws;
    int*    idxbuf = (int*)ws;                                   // @0    : 1 MB
    float*  g0t    = (float*)(ws + (1 << 20));                   // @1 MB : 4 MB
    unsigned short* w11b = (unsigned short*)(ws + (5 << 20));    // @5 MB : 32 KB
    unsigned short* w12b = (unsigned short*)(ws + (5 << 20) + 32768);   // 64 KB
    unsigned short* w20b = (unsigned short*)(ws + (5 << 20) + 98304);   // 256 KB
    unsigned short* pooled = (unsigned short*)(ws + (6 << 20));  // @6 MB : 16 MB
    unsigned short* f1t    = (unsigned short*)(ws + (22 << 20)); // @22 MB: 16 MB

    convert_weights<<<512, 256, 0, stream>>>(w11, w12, w20, w11b, w12b, w20b);
    f1_transpose<<<BB * 4 * 128, 256, 0, stream>>>(feature1, f1t);
    g0_kernel<<<BB * 64, 256, 0, stream>>>(feature2, w10, g0t);
    knn_wave<<<BB * 1024, 512, 0, stream>>>(pos1, pos2, idxbuf);

    main_kernel<<<BB * 512, 256, 0, stream>>>(
        idxbuf, g0t, pos1, pos2,
        w10, s10, b10, w11b, s11, b11, w12b, s12, b12, pooled);

    final_kernel<<<(BB * N1) / 64, 256, 0, stream>>>(pooled, f1t, w20b, s20, b20, out);
}

// Round 6
// 177.150 us; speedup vs baseline: 9.5960x; 1.1864x over previous
//
#include <hip/hip_runtime.h>

#define BB   4
#define N1   8192
#define N2   2048
#define KNN  8
#define C1   256
#define C2   512

typedef __attribute__((ext_vector_type(8))) short bf16x8;
typedef __attribute__((ext_vector_type(4))) float f32x4;

// hardware f32->bf16 (RNE) via native __bf16 cast
__device__ __forceinline__ unsigned short f2bf(float x) {
    __bf16 h = (__bf16)x;
    union { __bf16 b; unsigned short u; } v; v.b = h;
    return v.u;
}

// ---------------------------------------------------------------------------
// KNN: one wave per query. f32 scan with u32 keys (bits&~0x7FF | j), lane
// tracks its 3 smallest via a min/max insert network. 8 extraction rounds of
// u32 min-butterfly + one extra for the 9th. Certification: if the quantized
// d2-field of the 9th strictly exceeds the 8th's, the f32 top-8 SET provably
// equals the exact-f64 top-8 SET. Uncertified waves (~1 in 32k) fall back to
// the exact f64 path. Unrolls BOUNDED (4 / 2) to stay within the 64-VGPR cap
// of __launch_bounds__(512,8) -- full unroll spilled 378 MB to scratch (r5).
// ---------------------------------------------------------------------------
__global__ __launch_bounds__(512, 8) void knn_wave(const float* __restrict__ pos1,
                                                   const float* __restrict__ pos2,
                                                   int* __restrict__ idx_out) {
    __shared__ float pbuf[3 * N2];
    float* px = pbuf;
    float* py = pbuf + N2;
    float* pz = pbuf + 2 * N2;
    const int t = threadIdx.x;
    const int wv = t >> 6, lane = t & 63;
    const int b = blockIdx.x >> 10;
    const int n = ((blockIdx.x & 1023) << 3) + wv;

    const float* p2b = pos2 + (size_t)b * 3 * N2;
    for (int i = t; i < 3 * N2; i += 512) pbuf[i] = p2b[i];
    __syncthreads();

    const float* p1b = pos1 + (size_t)b * 3 * N1;
    const float qx = p1b[n], qy = p1b[N1 + n], qz = p1b[2 * N1 + n];

    const unsigned INF32 = 0xFFFFFFFFu;
    unsigned m1 = INF32, m2 = INF32, m3 = INF32;

#pragma unroll 4
    for (int i = 0; i < 32; ++i) {
        const int j = i * 64 + lane;
        float dx = px[j] - qx, dy = py[j] - qy, dz = pz[j] - qz;
        float d2 = fmaf(dx, dx, fmaf(dy, dy, dz * dz));
        unsigned k = (__float_as_uint(d2) & 0xFFFFF800u) | (unsigned)j;
        unsigned t1 = m1 < k ? m1 : k;
        unsigned t2 = m1 < k ? k : m1;
        unsigned u2 = m2 < t2 ? m2 : t2;
        unsigned u3 = m2 < t2 ? t2 : m2;
        m3 = m3 < u3 ? m3 : u3;
        m1 = t1; m2 = u2;
    }

    int* o = idx_out + ((size_t)b * N1 + n) * KNN;
    unsigned prev = 0;
#pragma unroll 1
    for (int r = 0; r < KNN; ++r) {
        unsigned g = m1;
#pragma unroll
        for (int s = 32; s; s >>= 1) {
            unsigned v = (unsigned)__shfl_xor((int)g, s, 64);
            g = v < g ? v : g;
        }
        if (lane == 0) o[r] = (int)(g & 0x7FFu);
        prev = g;
        bool w = (m1 == g);
        m1 = w ? m2 : m1;
        m2 = w ? m3 : m2;
        m3 = w ? INF32 : m3;
        if (m1 == INF32) {                       // tracked set exhausted (rare)
            unsigned a1 = INF32, a2 = INF32, a3 = INF32;
#pragma unroll 2
            for (int i = 0; i < 32; ++i) {
                const int j = i * 64 + lane;
                float dx = px[j] - qx, dy = py[j] - qy, dz = pz[j] - qz;
                float d2 = fmaf(dx, dx, fmaf(dy, dy, dz * dz));
                unsigned k = (__float_as_uint(d2) & 0xFFFFF800u) | (unsigned)j;
                if (k <= g) k = INF32;           // already extracted
                unsigned t1 = a1 < k ? a1 : k;
                unsigned t2 = a1 < k ? k : a1;
                unsigned u2 = a2 < t2 ? a2 : t2;
                unsigned u3 = a2 < t2 ? t2 : a2;
                a3 = a3 < u3 ? a3 : u3;
                a1 = t1; a2 = u2;
            }
            m1 = a1; m2 = a2; m3 = a3;
        }
    }
    unsigned g9 = m1;
#pragma unroll
    for (int s = 32; s; s >>= 1) {
        unsigned v = (unsigned)__shfl_xor((int)g9, s, 64);
        g9 = v < g9 ? v : g9;
    }
    if ((g9 & 0xFFFFF800u) != (prev & 0xFFFFF800u))
        return;                                   // certified (wave-uniform)

    // ---- exact f64 fallback (wave-uniform, ~1 wave per 32k) ----
    {
        const double qxd = (double)qx, qyd = (double)qy, qzd = (double)qz;
        const unsigned long long INF64 = ~0ull;
        unsigned long long M1 = INF64, M2 = INF64;
#pragma unroll 2
        for (int i = 0; i < 32; ++i) {
            const int j = i * 64 + lane;
            double dx = (double)px[j] - qxd;
            double dy = (double)py[j] - qyd;
            double dz = (double)pz[j] - qzd;
            double d2 = dx * dx + dy * dy + dz * dz;
            unsigned long long k =
                (((unsigned long long)__double_as_longlong(d2)) & ~2047ull) | (unsigned)j;
            bool pa = k < M1, pb = k < M2;
            M2 = pa ? M1 : (pb ? k : M2);
            M1 = pa ? k : M1;
        }
#pragma unroll 1
        for (int r = 0; r < KNN; ++r) {
            unsigned long long g = M1;
#pragma unroll
            for (int s = 32; s; s >>= 1) {
                unsigned long long v = __shfl_xor(g, s, 64);
                g = v < g ? v : g;
            }
            if (lane == 0) o[r] = (int)(g & 2047ull);
            if (M1 == g) {
                if (M2 != INF64) { M1 = M2; M2 = INF64; }
                else {
                    M1 = INF64; M2 = INF64;
#pragma unroll 2
                    for (int i = 0; i < 32; ++i) {
                        const int j = i * 64 + lane;
                        double dx = (double)px[j] - qxd;
                        double dy = (double)py[j] - qyd;
                        double dz = (double)pz[j] - qzd;
                        double d2 = dx * dx + dy * dy + dz * dz;
                        unsigned long long k =
                            (((unsigned long long)__double_as_longlong(d2)) & ~2047ull) | (unsigned)j;
                        if (k <= g) k = INF64;
                        bool pa = k < M1, pb = k < M2;
                        M2 = pa ? M1 : (pb ? k : M2);
                        M1 = pa ? k : M1;
                    }
                }
            }
        }
    }
}

// ---------------------------------------------------------------------------
// G0t[b][j][c] = sum_i feature2[b][i][j] * w1_0[c][i]   (fp32, point-major)
// ---------------------------------------------------------------------------
__global__ __launch_bounds__(256) void g0_kernel(const float* __restrict__ f2,
                                                 const float* __restrict__ w10,
                                                 float* __restrict__ g0t) {
    __shared__ float At[32][36];
    __shared__ float Wt[32][132];
    const int t = threadIdx.x;
    const int b = blockIdx.x >> 6;
    const int jt = (blockIdx.x & 63) * 32;
    const float* A = f2 + (size_t)b * C2 * N2;

    float acc[4][4];
#pragma unroll
    for (int r = 0; r < 4; ++r)
#pragma unroll
        for (int s = 0; s < 4; ++s) acc[r][s] = 0.f;

    const int lj = t & 31, li4 = (t >> 5) * 4;
    const int wc = t >> 1, wih = (t & 1) * 16;
    const int jg = t & 7, cg = t >> 3;

    for (int i0 = 0; i0 < C2; i0 += 32) {
        __syncthreads();
#pragma unroll
        for (int u = 0; u < 4; ++u)
            At[li4 + u][lj] = A[(size_t)(i0 + li4 + u) * N2 + jt + lj];
#pragma unroll
        for (int u = 0; u < 16; ++u)
            Wt[wih + u][wc] = w10[(size_t)wc * 515 + i0 + wih + u];
        __syncthreads();
#pragma unroll
        for (int ii = 0; ii < 32; ++ii) {
            float a[4], w[4];
            *(float4*)&a[0] = *(const float4*)&At[ii][jg * 4];
            *(float4*)&w[0] = *(const float4*)&Wt[ii][cg * 4];
#pragma unroll
            for (int r = 0; r < 4; ++r)
#pragma unroll
                for (int s = 0; s < 4; ++s) acc[r][s] += a[r] * w[s];
        }
    }
#pragma unroll
    for (int r = 0; r < 4; ++r) {
        int j = jt + jg * 4 + r;
        *(float4*)&g0t[((size_t)b * N2 + j) * 128 + cg * 4] =
            make_float4(acc[r][0], acc[r][1], acc[r][2], acc[r][3]);
    }
}

// ---------------------------------------------------------------------------
__global__ __launch_bounds__(256) void convert_weights(const float* __restrict__ w11,
                                                       const float* __restrict__ w12,
                                                       const float* __restrict__ w20,
                                                       unsigned short* __restrict__ w11b,
                                                       unsigned short* __restrict__ w12b,
                                                       unsigned short* __restrict__ w20b) {
    int i = blockIdx.x * 256 + threadIdx.x;
    if (i < 16384)  w11b[i] = f2bf(w11[i]);
    if (i < 32768)  w12b[i] = f2bf(w12[i]);
    if (i < 131072) w20b[i] = f2bf(w20[i]);
}

// ---------------------------------------------------------------------------
// f1 transpose: [B][256c][8192n] f32 -> [B*N1][256] bf16, 64x64 tiles.
// ---------------------------------------------------------------------------
__global__ __launch_bounds__(256) void f1_transpose(const float* __restrict__ f1,
                                                    unsigned short* __restrict__ f1t) {
    __shared__ float tile[64][65];
    const int t = threadIdx.x;
    const int b  = blockIdx.x >> 9;
    const int c0 = ((blockIdx.x >> 7) & 3) * 64;
    const int n0 = (blockIdx.x & 127) * 64;

    {
        const int c = t >> 2, ng = (t & 3) * 16;
        const float* src = f1 + ((size_t)b * C1 + c0 + c) * N1 + n0 + ng;
#pragma unroll
        for (int u = 0; u < 4; ++u)
            *(float4*)&tile[c][ng + u * 4] = *(const float4*)(src + u * 4);
    }
    __syncthreads();
    {
        const int n = t >> 2, cg = (t & 3) * 16;
        unsigned short v[16];
#pragma unroll
        for (int u = 0; u < 16; ++u) v[u] = f2bf(tile[cg + u][n]);
        unsigned short* dst = f1t + ((size_t)b * N1 + n0 + n) * 256 + c0 + cg;
        *(bf16x8*)dst       = *(bf16x8*)&v[0];
        *(bf16x8*)(dst + 8) = *(bf16x8*)&v[8];
    }
}

// ---------------------------------------------------------------------------
// Main fused kernel: 16 queries (128 neighbor-points) per block, 4 waves.
// h0 gather -> L1 (MFMA) -> L2 (MFMA) + max_k -> pooled (bf16, global).
// ---------------------------------------------------------------------------
__global__ __launch_bounds__(256, 4) void main_kernel(
    const int* __restrict__ idxbuf, const float* __restrict__ g0t,
    const float* __restrict__ pos1, const float* __restrict__ pos2,
    const float* __restrict__ w10, const float* __restrict__ s10, const float* __restrict__ b10,
    const unsigned short* __restrict__ w11b, const float* __restrict__ s11, const float* __restrict__ b11,
    const unsigned short* __restrict__ w12b, const float* __restrict__ s12, const float* __restrict__ b12,
    unsigned short* __restrict__ pooled) {

    __shared__ __align__(16) char smem[37120];
    char* sa = smem;                                         // [128][128] bf16 swz
    float* swp = (float*)(smem + 32768);                     // [5][128]
    float* spd = (float*)(smem + 35328);                     // [128][3]
    unsigned short* sidx = (unsigned short*)(smem + 36864);  // [128]

    const int t = threadIdx.x;
    const int lane = t & 63;
    const int wv = t >> 6;
    const int l15 = lane & 15;
    const int lk = lane >> 4;
    const int b = blockIdx.x >> 9;
    const int n0 = (blockIdx.x & 511) << 4;

    if (t < 128) {
        sidx[t] = (unsigned short)idxbuf[((size_t)b * N1 + n0 + (t >> 3)) * KNN + (t & 7)];
        swp[t]       = w10[(size_t)t * 515 + 512];
        swp[128 + t] = w10[(size_t)t * 515 + 513];
        swp[256 + t] = w10[(size_t)t * 515 + 514];
        swp[384 + t] = s10[t];
        swp[512 + t] = b10[t];
    }
    __syncthreads();
    if (t < 128) {
        int j = sidx[t];
        int n = n0 + (t >> 3);
        const float* p2b = pos2 + (size_t)b * 3 * N2;
        const float* p1b = pos1 + (size_t)b * 3 * N1;
        spd[t * 3 + 0] = p2b[j] - p1b[n];
        spd[t * 3 + 1] = p2b[N2 + j] - p1b[N1 + n];
        spd[t * 3 + 2] = p2b[2 * N2 + j] - p1b[2 * N1 + n];
    }
    __syncthreads();

    // ---- Phase A: h0 = relu(bn(g0[j] + Wp*pd)) -> bf16 swz in sa ----
    {
        const int ch0 = (t & 15) * 8;
        const float* g0b = g0t + (size_t)b * N2 * 128;
#pragma unroll
        for (int it = 0; it < 8; ++it) {
            int p = it * 16 + (t >> 4);
            int j = sidx[p];
            const float* gp = g0b + (size_t)j * 128 + ch0;
            float g[8];
            *(float4*)&g[0] = *(const float4*)gp;
            *(float4*)&g[4] = *(const float4*)(gp + 4);
            float pdx = spd[p * 3], pdy = spd[p * 3 + 1], pdz = spd[p * 3 + 2];
            bf16x8 pk;
#pragma unroll
            for (int u = 0; u < 8; ++u) {
                int c = ch0 + u;
                float v = g[u] + swp[c] * pdx + swp[128 + c] * pdy + swp[256 + c] * pdz;
                v = swp[384 + c] * v + swp[512 + c];
                v = v > 0.f ? v : 0.f;
                pk[u] = (short)f2bf(v);
            }
            int byte = (p * 256 + ch0 * 2) ^ ((p & 7) << 4);
            *(bf16x8*)(sa + byte) = pk;
        }
    }
    __syncthreads();

    const f32x4 zf = {0.f, 0.f, 0.f, 0.f};

    // ---- Layer 1: M=128 N=128 K=128 ----
    {
        f32x4 acc[2][8];
#pragma unroll
        for (int m = 0; m < 8; ++m) { acc[0][m] = zf; acc[1][m] = zf; }
        const int nb = wv * 32;
#pragma unroll 2
        for (int k0 = 0; k0 < 4; ++k0) {
            bf16x8 bf0 = *(const bf16x8*)(w11b + (size_t)(nb + l15) * 128 + k0 * 32 + lk * 8);
            bf16x8 bf1 = *(const bf16x8*)(w11b + (size_t)(nb + 16 + l15) * 128 + k0 * 32 + lk * 8);
#pragma unroll
            for (int m = 0; m < 8; ++m) {
                int row = m * 16 + l15;
                int byte = (row * 256 + k0 * 64 + lk * 16) ^ ((row & 7) << 4);
                bf16x8 af = *(const bf16x8*)(sa + byte);
                acc[0][m] = __builtin_amdgcn_mfma_f32_16x16x32_bf16(af, bf0, acc[0][m], 0, 0, 0);
                acc[1][m] = __builtin_amdgcn_mfma_f32_16x16x32_bf16(af, bf1, acc[1][m], 0, 0, 0);
            }
        }
        __syncthreads();   // all waves done reading h0
#pragma unroll
        for (int nt = 0; nt < 2; ++nt) {
            int c = nb + nt * 16 + l15;
            float sc = s11[c], bi = b11[c];
#pragma unroll
            for (int m = 0; m < 8; ++m) {
#pragma unroll
                for (int r = 0; r < 4; ++r) {
                    int row = m * 16 + lk * 4 + r;
                    float v = sc * acc[nt][m][r] + bi;
                    v = v > 0.f ? v : 0.f;
                    int byte = (row * 256 + c * 2) ^ ((row & 7) << 4);
                    *(unsigned short*)(sa + byte) = f2bf(v);
                }
            }
        }
    }
    __syncthreads();

    // ---- Layer 2: M=128 N=256 K=128; bn/relu, max over k, write pooled ----
    unsigned short* pb = pooled + ((size_t)b * N1 + n0) * 256;
#pragma unroll 1
    for (int h = 0; h < 2; ++h) {
        f32x4 acc2[2][8];
#pragma unroll
        for (int m = 0; m < 8; ++m) { acc2[0][m] = zf; acc2[1][m] = zf; }
        const int nb = h * 128 + wv * 32;
#pragma unroll 2
        for (int k0 = 0; k0 < 4; ++k0) {
            bf16x8 bf0 = *(const bf16x8*)(w12b + (size_t)(nb + l15) * 128 + k0 * 32 + lk * 8);
            bf16x8 bf1 = *(const bf16x8*)(w12b + (size_t)(nb + 16 + l15) * 128 + k0 * 32 + lk * 8);
#pragma unroll
            for (int m = 0; m < 8; ++m) {
                int row = m * 16 + l15;
                int byte = (row * 256 + k0 * 64 + lk * 16) ^ ((row & 7) << 4);
                bf16x8 af = *(const bf16x8*)(sa + byte);
                acc2[0][m] = __builtin_amdgcn_mfma_f32_16x16x32_bf16(af, bf0, acc2[0][m], 0, 0, 0);
                acc2[1][m] = __builtin_amdgcn_mfma_f32_16x16x32_bf16(af, bf1, acc2[1][m], 0, 0, 0);
            }
        }
#pragma unroll
        for (int nt = 0; nt < 2; ++nt) {
            int c = nb + nt * 16 + l15;
            float sc = s12[c], bi = b12[c];
#pragma unroll
            for (int m = 0; m < 8; ++m) {
                float mx = 0.f;
#pragma unroll
                for (int r = 0; r < 4; ++r) {
                    float v = sc * acc2[nt][m][r] + bi;
                    v = v > 0.f ? v : 0.f;
                    mx = fmaxf(mx, v);
                }
                mx = fmaxf(mx, __shfl_xor(mx, 16, 64));
                if ((lk & 1) == 0) {
                    int q = m * 2 + (lk >> 1);
                    pb[(size_t)q * 256 + c] = f2bf(mx);
                }
            }
        }
    }
}

// ---------------------------------------------------------------------------
// Final layer: out[b][o][n] = relu(s*(W20 . [pooled|f1t]) + b)
// ---------------------------------------------------------------------------
__global__ __launch_bounds__(256, 4) void final_kernel(
    const unsigned short* __restrict__ pooled,
    const unsigned short* __restrict__ f1t,
    const unsigned short* __restrict__ w20b,
    const float* __restrict__ s20, const float* __restrict__ b20,
    float* __restrict__ out) {

    __shared__ __align__(16) char sA[16384];   // [64][128] bf16 swz
    const int t = threadIdx.x;
    const int lane = t & 63;
    const int wv = t >> 6;
    const int l15 = lane & 15;
    const int lk = lane >> 4;
    const int n0g = blockIdx.x * 64;
    const int b = n0g >> 13;
    const int n0 = n0g & (N1 - 1);
    const int obase = wv * 64;

    f32x4 acc[4][4];
    const f32x4 zf = {0.f, 0.f, 0.f, 0.f};
#pragma unroll
    for (int m = 0; m < 4; ++m)
#pragma unroll
        for (int ot = 0; ot < 4; ++ot) acc[m][ot] = zf;

#pragma unroll 1
    for (int chunk = 0; chunk < 4; ++chunk) {
        const unsigned short* src = (chunk < 2) ? pooled : f1t;
        const int kc = (chunk & 1) * 128;
        __syncthreads();
        {
            const int row = t >> 2, seg = t & 3;
            const unsigned short* sp = src + ((size_t)n0g + row) * 256 + kc + seg * 32;
            bf16x8 v0 = *(const bf16x8*)sp;
            bf16x8 v1 = *(const bf16x8*)(sp + 8);
            bf16x8 v2 = *(const bf16x8*)(sp + 16);
            bf16x8 v3 = *(const bf16x8*)(sp + 24);
            const int base = row * 256 + seg * 64;
            const int x = (row & 7) << 4;
            *(bf16x8*)(sA + ((base)      ^ x)) = v0;
            *(bf16x8*)(sA + ((base + 16) ^ x)) = v1;
            *(bf16x8*)(sA + ((base + 32) ^ x)) = v2;
            *(bf16x8*)(sA + ((base + 48) ^ x)) = v3;
        }
        __syncthreads();
        const int kg = chunk * 128;
#pragma unroll
        for (int k0 = 0; k0 < 4; ++k0) {
            bf16x8 bfr[4];
#pragma unroll
            for (int ot = 0; ot < 4; ++ot)
                bfr[ot] = *(const bf16x8*)(w20b + (size_t)(obase + ot * 16 + l15) * 512 + kg + k0 * 32 + lk * 8);
#pragma unroll
            for (int m = 0; m < 4; ++m) {
                int row = m * 16 + l15;
                bf16x8 af = *(const bf16x8*)(sA + ((row * 256 + k0 * 64 + lk * 16) ^ ((row & 7) << 4)));
#pragma unroll
                for (int ot = 0; ot < 4; ++ot)
                    acc[m][ot] = __builtin_amdgcn_mfma_f32_16x16x32_bf16(af, bfr[ot], acc[m][ot], 0, 0, 0);
            }
        }
    }

#pragma unroll
    for (int ot = 0; ot < 4; ++ot) {
        int o = obase + ot * 16 + l15;
        float sc = s20[o], bi = b20[o];
#pragma unroll
        for (int m = 0; m < 4; ++m) {
            float4 ov;
            float v0 = sc * acc[m][ot][0] + bi; ov.x = v0 > 0.f ? v0 : 0.f;
            float v1 = sc * acc[m][ot][1] + bi; ov.y = v1 > 0.f ? v1 : 0.f;
            float v2 = sc * acc[m][ot][2] + bi; ov.z = v2 > 0.f ? v2 : 0.f;
            float v3 = sc * acc[m][ot][3] + bi; ov.w = v3 > 0.f ? v3 : 0.f;
            *(float4*)(out + ((size_t)b * 256 + o) * N1 + n0 + m * 16 + lk * 4) = ov;
        }
    }
}

// ---------------------------------------------------------------------------
extern "C" void kernel_launch(void* const* d_in, const int* in_sizes, int n_in,
                              void* d_out, int out_size, void* d_ws, size_t ws_size,
                              hipStream_t stream) {
    (void)in_sizes; (void)n_in; (void)out_size; (void)ws_size;
    const float* pos1     = (const float*)d_in[0];
    const float* pos2     = (const float*)d_in[1];
    const float* feature1 = (const float*)d_in[2];
    const float* feature2 = (const float*)d_in[3];
    const float* w10 = (const float*)d_in[4];
    const float* s10 = (const float*)d_in[5];
    const float* b10 = (const float*)d_in[6];
    const float* w11 = (const float*)d_in[7];
    const float* s11 = (const float*)d_in[8];
    const float* b11 = (const float*)d_in[9];
    const float* w12 = (const float*)d_in[10];
    const float* s12 = (const float*)d_in[11];
    const float* b12 = (const float*)d_in[12];
    const float* w20 = (const float*)d_in[13];
    const float* s20 = (const float*)d_in[14];
    const float* b20 = (const float*)d_in[15];
    float* out = (float*)d_out;

    char* ws = (char*)d_ws;
    int*    idxbuf = (int*)ws;                                   // @0    : 1 MB
    float*  g0t    = (float*)(ws + (1 << 20));                   // @1 MB : 4 MB
    unsigned short* w11b = (unsigned short*)(ws + (5 << 20));    // @5 MB : 32 KB
    unsigned short* w12b = (unsigned short*)(ws + (5 << 20) + 32768);   // 64 KB
    unsigned short* w20b = (unsigned short*)(ws + (5 << 20) + 98304);   // 256 KB
    unsigned short* pooled = (unsigned short*)(ws + (6 << 20));  // @6 MB : 16 MB
    unsigned short* f1t    = (unsigned short*)(ws + (22 << 20)); // @22 MB: 16 MB

    convert_weights<<<512, 256, 0, stream>>>(w11, w12, w20, w11b, w12b, w20b);
    f1_transpose<<<BB * 4 * 128, 256, 0, stream>>>(feature1, f1t);
    g0_kernel<<<BB * 64, 256, 0, stream>>>(feature2, w10, g0t);
    knn_wave<<<BB * 1024, 512, 0, stream>>>(pos1, pos2, idxbuf);

    main_kernel<<<BB * 512, 256, 0, stream>>>(
        idxbuf, g0t, pos1, pos2,
        w10, s10, b10, w11b, s11, b11, w12b, s12, b12, pooled);

    final_kernel<<<(BB * N1) / 64, 256, 0, stream>>>(pooled, f1t, w20b, s20, b20, out);
}